// Round 4
// baseline (698.227 us; speedup 1.0000x reference)
//
#include <hip/hip_runtime.h>
#include <hip/hip_bf16.h>
#include <cstddef>

// Problem constants (fixed-shape problem)
constexpr int N_NODES = 50000;
constexpr int N_EDGES = 800000;
constexpr int IN_DIM  = 128;
constexpr int HID     = 64;
constexpr int HEADS   = 4;
constexpr int F1      = HEADS * HID;  // 256
constexpr int EMB     = 128;
constexpr int N_GRAPHS = 64;

constexpr int DEG_BLOCKS  = (N_EDGES + 255) / 256;   // 3125
constexpr int GEMM1_BLOCKS = (N_NODES + 63) / 64;    // 782
constexpr int SCAT_BLOCKS  = (N_EDGES + 255) / 256;  // 3125

typedef __bf16 bf16x8 __attribute__((ext_vector_type(8)));
typedef float  f32x4  __attribute__((ext_vector_type(4)));

__device__ __forceinline__ float lrelu(float x) { return x > 0.f ? x : 0.2f * x; }
__device__ __forceinline__ float eluf(float x)  { return x > 0.f ? x : expm1f(x); }

// ---------------------------------------------------------------------------
// B-pack body: B [K x Ncols] f32 -> per-lane MFMA B-fragments, hi/lo bf16.
// lane -> n = t*16 + (lane&15), k = kk*32 + (lane>>4)*8 + j
// ---------------------------------------------------------------------------
__device__ __forceinline__ void pack_body(const float* __restrict__ B,
                                          __bf16* __restrict__ hi,
                                          __bf16* __restrict__ lo,
                                          int pblk, int NT, int KK, int Ncols) {
    const int gid = pblk * 256 + threadIdx.x;
    if (gid >= NT * KK * 64) return;
    const int lane = gid & 63;
    const int rem  = gid >> 6;
    const int kk   = rem % KK;
    const int t    = rem / KK;
    const int n    = t * 16 + (lane & 15);
    const int k0   = kk * 32 + (lane >> 4) * 8;
#pragma unroll
    for (int j = 0; j < 8; j++) {
        const float v = B[(size_t)(k0 + j) * Ncols + n];
        const __bf16 h = (__bf16)v;
        hi[(size_t)gid * 8 + j] = h;
        lo[(size_t)gid * 8 + j] = (__bf16)(v - (float)h);
    }
}

// ---------------------------------------------------------------------------
// prep: [deg histogram | pack W1 | pack W2] by block range (independent work)
// ---------------------------------------------------------------------------
__global__ __launch_bounds__(256) void prep_kernel(const int* __restrict__ ei,
                                                   int* __restrict__ deg,
                                                   const float* __restrict__ W1,
                                                   __bf16* __restrict__ B1h,
                                                   __bf16* __restrict__ B1l,
                                                   const float* __restrict__ W2,
                                                   __bf16* __restrict__ B2h,
                                                   __bf16* __restrict__ B2l) {
    const int b = blockIdx.x;
    if (b < DEG_BLOCKS) {
        const int e = b * 256 + threadIdx.x;
        if (e < N_EDGES) atomicAdd(&deg[ei[N_EDGES + e]], 1);
        return;
    }
    const int pb = b - DEG_BLOCKS;
    if (pb < 16) pack_body(W1, B1h, B1l, pb, F1 / 16, IN_DIM / 32, F1);
    else         pack_body(W2, B2h, B2l, pb - 16, EMB / 16, F1 / 32, EMB);
}

// ---------------------------------------------------------------------------
// Single-block scan: off = exclusive prefix of deg; also zeroes cur.
// ---------------------------------------------------------------------------
__global__ __launch_bounds__(1024) void scan_kernel(const int* __restrict__ deg,
                                                    int* __restrict__ off,
                                                    int* __restrict__ cur, int N) {
    __shared__ int sums[1024];
    const int t = threadIdx.x;
    const int chunk = (N + 1023) / 1024;
    const int begin = t * chunk;
    const int end = min(begin + chunk, N);
    int s = 0;
    for (int i = begin; i < end; i++) s += deg[i];
    sums[t] = s;
    __syncthreads();
    for (int o = 1; o < 1024; o <<= 1) {
        int v = (t >= o) ? sums[t - o] : 0;
        __syncthreads();
        sums[t] += v;
        __syncthreads();
    }
    int excl = (t == 0) ? 0 : sums[t - 1];
    for (int i = begin; i < end; i++) {
        off[i] = excl;
        cur[i] = 0;
        excl += deg[i];
    }
    if (t == 1023) off[N] = sums[1023];
}

// ---------------------------------------------------------------------------
// Split-bf16 MFMA GEMM + fused attention logits.
// C = op(A) @ B  (op = identity or ELU(a+bias[k]));
// as/ad[row,h] = sum_col C[row,col] * avec_{s,d}[col]  (NH heads, head=col/HD).
// 4 waves/block, wave w owns rows [blk*64 + w*16, +16).
// ---------------------------------------------------------------------------
template <int NT, int KK, int NH, bool ELU_A>
__device__ __forceinline__ void gemm_alpha_body(int blk,
                                                const float* __restrict__ A,
                                                const __bf16* __restrict__ Bh,
                                                const __bf16* __restrict__ Bl,
                                                const float* __restrict__ bias,
                                                const float* __restrict__ avs,
                                                const float* __restrict__ avd,
                                                float* __restrict__ C,
                                                float* __restrict__ as_out,
                                                float* __restrict__ ad_out, int M) {
    constexpr int Ncols = NT * 16;
    constexpr int K = KK * 32;
    const int tid  = threadIdx.x;
    const int wave = tid >> 6, lane = tid & 63;
    const int quad = lane >> 4, l16 = lane & 15;
    const int rowA = min(blk * 64 + wave * 16 + l16, M - 1);

    f32x4 acc[NT];
#pragma unroll
    for (int t = 0; t < NT; t++) acc[t] = (f32x4){0.f, 0.f, 0.f, 0.f};

    for (int kk = 0; kk < KK; kk++) {
        const int k0 = kk * 32 + quad * 8;
        float a8[8];
        *(float4*)&a8[0] = *(const float4*)&A[(size_t)rowA * K + k0];
        *(float4*)&a8[4] = *(const float4*)&A[(size_t)rowA * K + k0 + 4];
        if (ELU_A) {
#pragma unroll
            for (int j = 0; j < 8; j++) a8[j] = eluf(a8[j] + bias[k0 + j]);
        }
        bf16x8 ah, al;
#pragma unroll
        for (int j = 0; j < 8; j++) {
            const __bf16 h = (__bf16)a8[j];
            ah[j] = h;
            al[j] = (__bf16)(a8[j] - (float)h);
        }
#pragma unroll
        for (int t = 0; t < NT; t++) {
            const size_t bi = ((size_t)(t * KK + kk) * 64 + lane) * 8;
            bf16x8 bhv = *(const bf16x8*)&Bh[bi];
            bf16x8 blv = *(const bf16x8*)&Bl[bi];
            acc[t] = __builtin_amdgcn_mfma_f32_16x16x32_bf16(ah, bhv, acc[t], 0, 0, 0);
            acc[t] = __builtin_amdgcn_mfma_f32_16x16x32_bf16(al, bhv, acc[t], 0, 0, 0);
            acc[t] = __builtin_amdgcn_mfma_f32_16x16x32_bf16(ah, blv, acc[t], 0, 0, 0);
        }
    }

    // C/D layout: col = t*16 + l16, row = rowS + r (r = reg idx)
    const int rowS = blk * 64 + wave * 16 + quad * 4;
#pragma unroll
    for (int t = 0; t < NT; t++) {
#pragma unroll
        for (int r = 0; r < 4; r++) {
            const int rr = rowS + r;
            if (rr < M) C[(size_t)rr * Ncols + t * 16 + l16] = acc[t][r];
        }
    }

    // Fused attention logits
#pragma unroll
    for (int r = 0; r < 4; r++) {
        float ps[NH], pd[NH];
#pragma unroll
        for (int h = 0; h < NH; h++) { ps[h] = 0.f; pd[h] = 0.f; }
#pragma unroll
        for (int t = 0; t < NT; t++) {
            const int h = (t * 16) / (Ncols / NH);  // head (l16 < 16 <= HD)
            const int col = t * 16 + l16;
            ps[h] += acc[t][r] * avs[col];
            pd[h] += acc[t][r] * avd[col];
        }
#pragma unroll
        for (int o = 1; o < 16; o <<= 1) {
#pragma unroll
            for (int h = 0; h < NH; h++) {
                ps[h] += __shfl_xor(ps[h], o);
                pd[h] += __shfl_xor(pd[h], o);
            }
        }
        const int rr = rowS + r;
        if (l16 == 0 && rr < M) {
#pragma unroll
            for (int h = 0; h < NH; h++) {
                as_out[rr * NH + h] = ps[h];
                ad_out[rr * NH + h] = pd[h];
            }
        }
    }
}

// gemm1(+alpha1) fused with CSR scatter in one dispatch (independent ranges)
__global__ __launch_bounds__(256) void gemm1_scatter_kernel(
        const float* __restrict__ A, const __bf16* __restrict__ Bh,
        const __bf16* __restrict__ Bl, const float* __restrict__ avs,
        const float* __restrict__ avd, float* __restrict__ C,
        float* __restrict__ as_out, float* __restrict__ ad_out, int M,
        const int* __restrict__ ei, const int* __restrict__ off,
        int* __restrict__ cur, int* __restrict__ col) {
    if (blockIdx.x < GEMM1_BLOCKS) {
        gemm_alpha_body<F1 / 16, IN_DIM / 32, HEADS, false>(
            blockIdx.x, A, Bh, Bl, nullptr, avs, avd, C, as_out, ad_out, M);
        return;
    }
    const int e = (blockIdx.x - GEMM1_BLOCKS) * 256 + threadIdx.x;
    if (e >= N_EDGES) return;
    const int s = ei[e], d = ei[N_EDGES + e];
    const int pos = atomicAdd(&cur[d], 1);
    col[off[d] + pos] = s;
}

__global__ __launch_bounds__(256) void gemm2_kernel(
        const float* __restrict__ A, const __bf16* __restrict__ Bh,
        const __bf16* __restrict__ Bl, const float* __restrict__ bias,
        const float* __restrict__ avs, const float* __restrict__ avd,
        float* __restrict__ C, float* __restrict__ as_out,
        float* __restrict__ ad_out, int M) {
    gemm_alpha_body<EMB / 16, F1 / 32, 1, true>(
        blockIdx.x, A, Bh, Bl, bias, avs, avd, C, as_out, ad_out, M);
}

// ---------------------------------------------------------------------------
// Layer-1 aggregation: one wave per dst node, float4/lane (256 ch),
// 2-edge unroll for memory-level parallelism. No atomics.
// ---------------------------------------------------------------------------
__global__ __launch_bounds__(256) void agg1_kernel(const int* __restrict__ off,
                                                   const int* __restrict__ col,
                                                   const float* __restrict__ h1,
                                                   const float* __restrict__ as1,
                                                   const float* __restrict__ ad1,
                                                   float* __restrict__ out1, int N) {
    const int w = (blockIdx.x * 256 + threadIdx.x) >> 6;
    const int lane = threadIdx.x & 63;
    if (w >= N) return;
    const int head = lane >> 4;
    const float ad = ad1[w * HEADS + head];

    float4 acc = make_float4(0.f, 0.f, 0.f, 0.f);
    float z = 0.f;
    {   // self-loop
        const float wt = expf(lrelu(as1[w * HEADS + head] + ad));
        float4 hv = *(const float4*)&h1[(size_t)w * F1 + lane * 4];
        acc.x += wt * hv.x; acc.y += wt * hv.y; acc.z += wt * hv.z; acc.w += wt * hv.w;
        z += wt;
    }
    const int jb = off[w], je = off[w + 1];
    int j = jb;
    for (; j + 1 < je; j += 2) {
        const int s0 = col[j], s1 = col[j + 1];
        const float w0 = expf(lrelu(as1[s0 * HEADS + head] + ad));
        const float w1 = expf(lrelu(as1[s1 * HEADS + head] + ad));
        float4 v0 = *(const float4*)&h1[(size_t)s0 * F1 + lane * 4];
        float4 v1 = *(const float4*)&h1[(size_t)s1 * F1 + lane * 4];
        acc.x += w0 * v0.x + w1 * v1.x;
        acc.y += w0 * v0.y + w1 * v1.y;
        acc.z += w0 * v0.z + w1 * v1.z;
        acc.w += w0 * v0.w + w1 * v1.w;
        z += w0 + w1;
    }
    if (j < je) {
        const int s0 = col[j];
        const float w0 = expf(lrelu(as1[s0 * HEADS + head] + ad));
        float4 v0 = *(const float4*)&h1[(size_t)s0 * F1 + lane * 4];
        acc.x += w0 * v0.x; acc.y += w0 * v0.y; acc.z += w0 * v0.z; acc.w += w0 * v0.w;
        z += w0;
    }
    const float inv = 1.f / z;
    float4 o = make_float4(acc.x * inv, acc.y * inv, acc.z * inv, acc.w * inv);
    *(float4*)&out1[(size_t)w * F1 + lane * 4] = o;
}

// Layer-2 aggregation: one wave per dst node, float2/lane (128 ch).
__global__ __launch_bounds__(256) void agg2_kernel(const int* __restrict__ off,
                                                   const int* __restrict__ col,
                                                   const float* __restrict__ g2,
                                                   const float* __restrict__ as2,
                                                   const float* __restrict__ ad2,
                                                   float* __restrict__ out2, int N) {
    const int w = (blockIdx.x * 256 + threadIdx.x) >> 6;
    const int lane = threadIdx.x & 63;
    if (w >= N) return;
    const float ad = ad2[w];

    float2 acc = make_float2(0.f, 0.f);
    float z = 0.f;
    {
        const float wt = expf(lrelu(as2[w] + ad));
        float2 hv = *(const float2*)&g2[(size_t)w * EMB + lane * 2];
        acc.x += wt * hv.x; acc.y += wt * hv.y;
        z += wt;
    }
    const int jb = off[w], je = off[w + 1];
    int j = jb;
    for (; j + 1 < je; j += 2) {
        const int s0 = col[j], s1 = col[j + 1];
        const float w0 = expf(lrelu(as2[s0] + ad));
        const float w1 = expf(lrelu(as2[s1] + ad));
        float2 v0 = *(const float2*)&g2[(size_t)s0 * EMB + lane * 2];
        float2 v1 = *(const float2*)&g2[(size_t)s1 * EMB + lane * 2];
        acc.x += w0 * v0.x + w1 * v1.x;
        acc.y += w0 * v0.y + w1 * v1.y;
        z += w0 + w1;
    }
    if (j < je) {
        const int s0 = col[j];
        const float w0 = expf(lrelu(as2[s0] + ad));
        float2 v0 = *(const float2*)&g2[(size_t)s0 * EMB + lane * 2];
        acc.x += w0 * v0.x; acc.y += w0 * v0.y;
        z += w0;
    }
    const float inv = 1.f / z;
    float2 o = make_float2(acc.x * inv, acc.y * inv);
    *(float2*)&out2[(size_t)w * EMB + lane * 2] = o;
}

// ---------------------------------------------------------------------------
// Pool + divide in one dispatch: block g binary-searches its node range in the
// sorted batch vector, accumulates ELU(out2 + b2) locally, writes out directly.
// ---------------------------------------------------------------------------
__global__ __launch_bounds__(256) void pooldiv_kernel(const float* __restrict__ out2,
                                                      const float* __restrict__ b2,
                                                      const int* __restrict__ batch,
                                                      float* __restrict__ out, int N) {
    const int g = blockIdx.x;
    const int c = threadIdx.x & 127;
    const int half = threadIdx.x >> 7;
    __shared__ float red[2][128];

    int lo, hi;
    {   // lower_bound(g), lower_bound(g+1)
        int l = 0, r = N;
        while (l < r) { int m = (l + r) >> 1; if (batch[m] < g) l = m + 1; else r = m; }
        lo = l;
        l = lo; r = N;
        while (l < r) { int m = (l + r) >> 1; if (batch[m] < g + 1) l = m + 1; else r = m; }
        hi = l;
    }
    const float bias = b2[c];
    float acc = 0.f;
    for (int n = lo + half; n < hi; n += 2) {
        float v = out2[(size_t)n * EMB + c] + bias;
        acc += (v > 0.f) ? v : expm1f(v);
    }
    red[half][c] = acc;
    __syncthreads();
    if (half == 0) {
        const float tot = red[0][c] + red[1][c];
        out[g * EMB + c] = tot / fmaxf((float)(hi - lo), 1.f);
    }
}

// ---------------------------------------------------------------------------
extern "C" void kernel_launch(void* const* d_in, const int* in_sizes, int n_in,
                              void* d_out, int out_size, void* d_ws, size_t ws_size,
                              hipStream_t stream) {
    const float* x      = (const float*)d_in[0];
    const int*   ei     = (const int*)d_in[1];
    const int*   batch  = (const int*)d_in[3];
    const float* W1     = (const float*)d_in[4];
    const float* a_src1 = (const float*)d_in[5];
    const float* a_dst1 = (const float*)d_in[6];
    const float* b1     = (const float*)d_in[7];
    const float* W2     = (const float*)d_in[8];
    const float* a_src2 = (const float*)d_in[9];
    const float* a_dst2 = (const float*)d_in[10];
    const float* b2     = (const float*)d_in[11];
    float* out = (float*)d_out;

    const int N = N_NODES, E = N_EDGES;

    size_t cur_off = 0;
    auto carve = [&](size_t bytes) {
        size_t o = cur_off;
        cur_off = (cur_off + bytes + 255) & ~(size_t)255;
        return (char*)d_ws + o;
    };
    int* deg     = (int*)carve((size_t)N * 4);
    const size_t zero_bytes = cur_off;  // only deg needs zeroing
    int* curp    = (int*)carve((size_t)N * 4);
    __bf16* B1h  = (__bf16*)carve((size_t)IN_DIM * F1 * 2);
    __bf16* B1l  = (__bf16*)carve((size_t)IN_DIM * F1 * 2);
    __bf16* B2h  = (__bf16*)carve((size_t)F1 * EMB * 2);
    __bf16* B2l  = (__bf16*)carve((size_t)F1 * EMB * 2);
    int* off     = (int*)carve((size_t)(N + 1) * 4);
    int* col     = (int*)carve((size_t)E * 4);
    float* h1    = (float*)carve((size_t)N * F1 * 4);
    float* out1  = (float*)carve((size_t)N * F1 * 4);
    float* g2    = (float*)carve((size_t)N * EMB * 4);
    float* out2  = (float*)carve((size_t)N * EMB * 4);
    float* as1   = (float*)carve((size_t)N * HEADS * 4);
    float* ad1   = (float*)carve((size_t)N * HEADS * 4);
    float* as2   = (float*)carve((size_t)N * 4);
    float* ad2   = (float*)carve((size_t)N * 4);

    hipMemsetAsync(deg, 0, zero_bytes, stream);

    // deg histogram + both weight packs (one dispatch)
    prep_kernel<<<DEG_BLOCKS + 32, 256, 0, stream>>>(ei, deg, W1, B1h, B1l, W2, B2h, B2l);
    scan_kernel<<<1, 1024, 0, stream>>>(deg, off, curp, N);

    // gemm1 + fused alpha1, and CSR scatter, in one dispatch
    gemm1_scatter_kernel<<<GEMM1_BLOCKS + SCAT_BLOCKS, 256, 0, stream>>>(
        x, B1h, B1l, a_src1, a_dst1, h1, as1, ad1, N, ei, off, curp, col);

    agg1_kernel<<<(N + 3) / 4, 256, 0, stream>>>(off, col, h1, as1, ad1, out1, N);

    // gemm2 (A = ELU(out1 + b1)) + fused alpha2
    gemm2_kernel<<<(N + 63) / 64, 256, 0, stream>>>(out1, B2h, B2l, b1, a_src2, a_dst2,
                                                    g2, as2, ad2, N);

    agg2_kernel<<<(N + 3) / 4, 256, 0, stream>>>(off, col, g2, as2, ad2, out2, N);

    // pool + divide (one dispatch, no atomics)
    pooldiv_kernel<<<N_GRAPHS, 256, 0, stream>>>(out2, b2, batch, out, N);
}

// Round 5
// 603.626 us; speedup vs baseline: 1.1567x; 1.1567x over previous
//
#include <hip/hip_runtime.h>
#include <hip/hip_bf16.h>
#include <cstddef>

// Problem constants (fixed-shape problem)
constexpr int N_NODES = 50000;
constexpr int N_EDGES = 800000;
constexpr int IN_DIM  = 128;
constexpr int HID     = 64;
constexpr int HEADS   = 4;
constexpr int F1      = HEADS * HID;  // 256
constexpr int EMB     = 128;
constexpr int N_GRAPHS = 64;

constexpr int DEG_BLOCKS   = (N_EDGES + 255) / 256;  // 3125
constexpr int GEMM1_BLOCKS = (N_NODES + 63) / 64;    // 782
constexpr int SCAT_BLOCKS  = (N_EDGES + 255) / 256;  // 3125
// per-head W1 fragment size (NT=4, KK=4): 4*4*64*8 bf16 elements
constexpr int W1_FRAG = 4 * 4 * 64 * 8;              // 8192

typedef __bf16 bf16x8 __attribute__((ext_vector_type(8)));
typedef float  f32x4  __attribute__((ext_vector_type(4)));

__device__ __forceinline__ float lrelu(float x) { return x > 0.f ? x : 0.2f * x; }
__device__ __forceinline__ float eluf(float x)  { return x > 0.f ? x : expm1f(x); }

// ---------------------------------------------------------------------------
// Pack a [K x 16*NT] submatrix of B (leading dim ld, origin col0) into
// per-lane MFMA B-fragments, split hi/lo bf16.
// lane -> n = col0 + t*16 + (lane&15), k = kk*32 + (lane>>4)*8 + j
// ---------------------------------------------------------------------------
__device__ __forceinline__ void pack_frag(const float* __restrict__ B,
                                          __bf16* __restrict__ hi,
                                          __bf16* __restrict__ lo,
                                          int pblk, int NT, int KK, int ld, int col0) {
    const int gid = pblk * 256 + threadIdx.x;
    if (gid >= NT * KK * 64) return;
    const int lane = gid & 63;
    const int rem  = gid >> 6;
    const int kk   = rem % KK;
    const int t    = rem / KK;
    const int n    = col0 + t * 16 + (lane & 15);
    const int k0   = kk * 32 + (lane >> 4) * 8;
#pragma unroll
    for (int j = 0; j < 8; j++) {
        const float v = B[(size_t)(k0 + j) * ld + n];
        const __bf16 h = (__bf16)v;
        hi[(size_t)gid * 8 + j] = h;
        lo[(size_t)gid * 8 + j] = (__bf16)(v - (float)h);
    }
}

// ---------------------------------------------------------------------------
// prep: [deg histogram | pack W1 per-head | pack W2] by block range.
// ---------------------------------------------------------------------------
__global__ __launch_bounds__(256) void prep_kernel(const int* __restrict__ ei,
                                                   int* __restrict__ deg,
                                                   const float* __restrict__ W1,
                                                   __bf16* __restrict__ B1h,
                                                   __bf16* __restrict__ B1l,
                                                   const float* __restrict__ W2,
                                                   __bf16* __restrict__ B2h,
                                                   __bf16* __restrict__ B2l) {
    const int b = blockIdx.x;
    if (b < DEG_BLOCKS) {
        const int e = b * 256 + threadIdx.x;
        if (e < N_EDGES) atomicAdd(&deg[ei[N_EDGES + e]], 1);
        return;
    }
    const int pb = b - DEG_BLOCKS;
    if (pb < 16) {
        // W1 head-block packs: head = pb/4, sub-block = pb%4 (NT=4, KK=4, ld=256)
        const int head = pb >> 2;
        pack_frag(W1, B1h + head * W1_FRAG, B1l + head * W1_FRAG,
                  pb & 3, 4, 4, F1, head * HID);
    } else {
        // W2 pack: NT=8, KK=8, ld=128 (16 blocks)
        pack_frag(W2, B2h, B2l, pb - 16, 8, 8, EMB, 0);
    }
}

// ---------------------------------------------------------------------------
// Single-block scan: off = exclusive prefix of deg; also zeroes cur.
// ---------------------------------------------------------------------------
__global__ __launch_bounds__(1024) void scan_kernel(const int* __restrict__ deg,
                                                    int* __restrict__ off,
                                                    int* __restrict__ cur, int N) {
    __shared__ int sums[1024];
    const int t = threadIdx.x;
    const int chunk = (N + 1023) / 1024;
    const int begin = t * chunk;
    const int end = min(begin + chunk, N);
    int s = 0;
    for (int i = begin; i < end; i++) s += deg[i];
    sums[t] = s;
    __syncthreads();
    for (int o = 1; o < 1024; o <<= 1) {
        int v = (t >= o) ? sums[t - o] : 0;
        __syncthreads();
        sums[t] += v;
        __syncthreads();
    }
    int excl = (t == 0) ? 0 : sums[t - 1];
    for (int i = begin; i < end; i++) {
        off[i] = excl;
        cur[i] = 0;
        excl += deg[i];
    }
    if (t == 1023) off[N] = sums[1023];
}

// ---------------------------------------------------------------------------
// Split-bf16 MFMA GEMM (+ optional C store) + fused attention logits.
// ---------------------------------------------------------------------------
template <int NT, int KK, int NH, bool ELU_A, bool STORE_C>
__device__ __forceinline__ void gemm_alpha_body(int blk,
                                                const float* __restrict__ A,
                                                const __bf16* __restrict__ Bh,
                                                const __bf16* __restrict__ Bl,
                                                const float* __restrict__ bias,
                                                const float* __restrict__ avs,
                                                const float* __restrict__ avd,
                                                float* __restrict__ C,
                                                float* __restrict__ as_out,
                                                float* __restrict__ ad_out, int M) {
    constexpr int Ncols = NT * 16;
    constexpr int K = KK * 32;
    const int tid  = threadIdx.x;
    const int wave = tid >> 6, lane = tid & 63;
    const int quad = lane >> 4, l16 = lane & 15;
    const int rowA = min(blk * 64 + wave * 16 + l16, M - 1);

    f32x4 acc[NT];
#pragma unroll
    for (int t = 0; t < NT; t++) acc[t] = (f32x4){0.f, 0.f, 0.f, 0.f};

    for (int kk = 0; kk < KK; kk++) {
        const int k0 = kk * 32 + quad * 8;
        float a8[8];
        *(float4*)&a8[0] = *(const float4*)&A[(size_t)rowA * K + k0];
        *(float4*)&a8[4] = *(const float4*)&A[(size_t)rowA * K + k0 + 4];
        if (ELU_A) {
#pragma unroll
            for (int j = 0; j < 8; j++) a8[j] = eluf(a8[j] + bias[k0 + j]);
        }
        bf16x8 ah, al;
#pragma unroll
        for (int j = 0; j < 8; j++) {
            const __bf16 h = (__bf16)a8[j];
            ah[j] = h;
            al[j] = (__bf16)(a8[j] - (float)h);
        }
#pragma unroll
        for (int t = 0; t < NT; t++) {
            const size_t bi = ((size_t)(t * KK + kk) * 64 + lane) * 8;
            bf16x8 bhv = *(const bf16x8*)&Bh[bi];
            bf16x8 blv = *(const bf16x8*)&Bl[bi];
            acc[t] = __builtin_amdgcn_mfma_f32_16x16x32_bf16(ah, bhv, acc[t], 0, 0, 0);
            acc[t] = __builtin_amdgcn_mfma_f32_16x16x32_bf16(al, bhv, acc[t], 0, 0, 0);
            acc[t] = __builtin_amdgcn_mfma_f32_16x16x32_bf16(ah, blv, acc[t], 0, 0, 0);
        }
    }

    // C/D layout: col = t*16 + l16, row = rowS + r
    const int rowS = blk * 64 + wave * 16 + quad * 4;
    if (STORE_C) {
#pragma unroll
        for (int t = 0; t < NT; t++) {
#pragma unroll
            for (int r = 0; r < 4; r++) {
                const int rr = rowS + r;
                if (rr < M) C[(size_t)rr * Ncols + t * 16 + l16] = acc[t][r];
            }
        }
    }

    // Fused attention logits
#pragma unroll
    for (int r = 0; r < 4; r++) {
        float ps[NH], pd[NH];
#pragma unroll
        for (int h = 0; h < NH; h++) { ps[h] = 0.f; pd[h] = 0.f; }
#pragma unroll
        for (int t = 0; t < NT; t++) {
            const int h = (t * 16) / (Ncols / NH);
            const int col = t * 16 + l16;
            ps[h] += acc[t][r] * avs[col];
            pd[h] += acc[t][r] * avd[col];
        }
#pragma unroll
        for (int o = 1; o < 16; o <<= 1) {
#pragma unroll
            for (int h = 0; h < NH; h++) {
                ps[h] += __shfl_xor(ps[h], o);
                pd[h] += __shfl_xor(pd[h], o);
            }
        }
        const int rr = rowS + r;
        if (l16 == 0 && rr < M) {
#pragma unroll
            for (int h = 0; h < NH; h++) {
                as_out[rr * NH + h] = ps[h];
                ad_out[rr * NH + h] = pd[h];
            }
        }
    }
}

// gemm1: A=x, computes h in-register, emits ONLY as1/ad1 (no C store).
// Fused with CSR scatter in one dispatch (independent block ranges).
__global__ __launch_bounds__(256) void gemm1_scatter_kernel(
        const float* __restrict__ A, const __bf16* __restrict__ Bh,
        const __bf16* __restrict__ Bl, const float* __restrict__ avs,
        const float* __restrict__ avd, float* __restrict__ as_out,
        float* __restrict__ ad_out, int M,
        const int* __restrict__ ei, const int* __restrict__ off,
        int* __restrict__ cur, int* __restrict__ col) {
    if (blockIdx.x < GEMM1_BLOCKS) {
        gemm_alpha_body<F1 / 16, IN_DIM / 32, HEADS, false, false>(
            blockIdx.x, A, Bh, Bl, nullptr, avs, avd, nullptr, as_out, ad_out, M);
        return;
    }
    const int e = (blockIdx.x - GEMM1_BLOCKS) * 256 + threadIdx.x;
    if (e >= N_EDGES) return;
    const int s = ei[e], d = ei[N_EDGES + e];
    const int pos = atomicAdd(&cur[d], 1);
    col[off[d] + pos] = s;
}

__global__ __launch_bounds__(256) void gemm2_kernel(
        const float* __restrict__ A, const __bf16* __restrict__ Bh,
        const __bf16* __restrict__ Bl, const float* __restrict__ bias,
        const float* __restrict__ avs, const float* __restrict__ avd,
        float* __restrict__ C, float* __restrict__ as_out,
        float* __restrict__ ad_out, int M) {
    gemm_alpha_body<EMB / 16, F1 / 32, 1, true, true>(
        blockIdx.x, A, Bh, Bl, bias, avs, avd, C, as_out, ad_out, M);
}

// ---------------------------------------------------------------------------
// Layer-1 x-aggregation: one wave per dst node. Gathers x rows (512 B) and
// accumulates 4 per-head weighted sums + softmax denominators; writes
// aggx[node][head][128] = (sum_e w_e x[src_e]) / z_h.   (Uses linearity:
// sum alpha (x@W1) = (sum alpha x) @ W1.)
// ---------------------------------------------------------------------------
__global__ __launch_bounds__(256) void agg1x_kernel(const int* __restrict__ off,
                                                    const int* __restrict__ col,
                                                    const float* __restrict__ x,
                                                    const float* __restrict__ as1,
                                                    const float* __restrict__ ad1,
                                                    float* __restrict__ aggx, int N) {
    const int w = (blockIdx.x * 256 + threadIdx.x) >> 6;
    const int lane = threadIdx.x & 63;
    if (w >= N) return;
    const float4 adv = *(const float4*)&ad1[w * HEADS];

    float2 acc[HEADS];
    float z[HEADS];
#pragma unroll
    for (int h = 0; h < HEADS; h++) { acc[h] = make_float2(0.f, 0.f); z[h] = 0.f; }

    // self-loop
    {
        const float4 asv = *(const float4*)&as1[w * HEADS];
        const float2 xv = *(const float2*)&x[(size_t)w * IN_DIM + lane * 2];
        const float w0 = expf(lrelu(asv.x + adv.x));
        const float w1 = expf(lrelu(asv.y + adv.y));
        const float w2 = expf(lrelu(asv.z + adv.z));
        const float w3 = expf(lrelu(asv.w + adv.w));
        acc[0].x += w0 * xv.x; acc[0].y += w0 * xv.y; z[0] += w0;
        acc[1].x += w1 * xv.x; acc[1].y += w1 * xv.y; z[1] += w1;
        acc[2].x += w2 * xv.x; acc[2].y += w2 * xv.y; z[2] += w2;
        acc[3].x += w3 * xv.x; acc[3].y += w3 * xv.y; z[3] += w3;
    }
    const int jb = off[w], je = off[w + 1];
    int j = jb;
    for (; j + 1 < je; j += 2) {
        const int s0 = col[j], s1 = col[j + 1];
        const float4 a0 = *(const float4*)&as1[s0 * HEADS];
        const float4 a1 = *(const float4*)&as1[s1 * HEADS];
        const float2 v0 = *(const float2*)&x[(size_t)s0 * IN_DIM + lane * 2];
        const float2 v1 = *(const float2*)&x[(size_t)s1 * IN_DIM + lane * 2];
        const float w00 = expf(lrelu(a0.x + adv.x)), w10 = expf(lrelu(a1.x + adv.x));
        const float w01 = expf(lrelu(a0.y + adv.y)), w11 = expf(lrelu(a1.y + adv.y));
        const float w02 = expf(lrelu(a0.z + adv.z)), w12 = expf(lrelu(a1.z + adv.z));
        const float w03 = expf(lrelu(a0.w + adv.w)), w13 = expf(lrelu(a1.w + adv.w));
        acc[0].x += w00 * v0.x + w10 * v1.x; acc[0].y += w00 * v0.y + w10 * v1.y; z[0] += w00 + w10;
        acc[1].x += w01 * v0.x + w11 * v1.x; acc[1].y += w01 * v0.y + w11 * v1.y; z[1] += w01 + w11;
        acc[2].x += w02 * v0.x + w12 * v1.x; acc[2].y += w02 * v0.y + w12 * v1.y; z[2] += w02 + w12;
        acc[3].x += w03 * v0.x + w13 * v1.x; acc[3].y += w03 * v0.y + w13 * v1.y; z[3] += w03 + w13;
    }
    if (j < je) {
        const int s0 = col[j];
        const float4 a0 = *(const float4*)&as1[s0 * HEADS];
        const float2 v0 = *(const float2*)&x[(size_t)s0 * IN_DIM + lane * 2];
        const float w00 = expf(lrelu(a0.x + adv.x));
        const float w01 = expf(lrelu(a0.y + adv.y));
        const float w02 = expf(lrelu(a0.z + adv.z));
        const float w03 = expf(lrelu(a0.w + adv.w));
        acc[0].x += w00 * v0.x; acc[0].y += w00 * v0.y; z[0] += w00;
        acc[1].x += w01 * v0.x; acc[1].y += w01 * v0.y; z[1] += w01;
        acc[2].x += w02 * v0.x; acc[2].y += w02 * v0.y; z[2] += w02;
        acc[3].x += w03 * v0.x; acc[3].y += w03 * v0.y; z[3] += w03;
    }
#pragma unroll
    for (int h = 0; h < HEADS; h++) {
        const float inv = 1.f / z[h];
        float2 o = make_float2(acc[h].x * inv, acc[h].y * inv);
        *(float2*)&aggx[((size_t)w * HEADS + h) * IN_DIM + lane * 2] = o;
    }
}

// ---------------------------------------------------------------------------
// Head-GEMM: out1[:, h*64:(h+1)*64] = aggx[:, h, :] @ W1[:, h*64:(h+1)*64]
// grid (node_blocks, 4 heads); NT=4, KK=4.
// ---------------------------------------------------------------------------
__global__ __launch_bounds__(256) void gemm_bd_kernel(const float* __restrict__ aggx,
                                                      const __bf16* __restrict__ B1h,
                                                      const __bf16* __restrict__ B1l,
                                                      float* __restrict__ out1, int M) {
    constexpr int NT = 4, KK = 4;
    const int head = blockIdx.y;
    const int blk = blockIdx.x;
    const int tid  = threadIdx.x;
    const int wave = tid >> 6, lane = tid & 63;
    const int quad = lane >> 4, l16 = lane & 15;
    const int rowA = min(blk * 64 + wave * 16 + l16, M - 1);
    const float* Arow = aggx + ((size_t)rowA * HEADS + head) * IN_DIM;
    const __bf16* Bh = B1h + head * W1_FRAG;
    const __bf16* Bl = B1l + head * W1_FRAG;

    f32x4 acc[NT];
#pragma unroll
    for (int t = 0; t < NT; t++) acc[t] = (f32x4){0.f, 0.f, 0.f, 0.f};

    for (int kk = 0; kk < KK; kk++) {
        const int k0 = kk * 32 + quad * 8;
        float a8[8];
        *(float4*)&a8[0] = *(const float4*)&Arow[k0];
        *(float4*)&a8[4] = *(const float4*)&Arow[k0 + 4];
        bf16x8 ah, al;
#pragma unroll
        for (int j = 0; j < 8; j++) {
            const __bf16 h = (__bf16)a8[j];
            ah[j] = h;
            al[j] = (__bf16)(a8[j] - (float)h);
        }
#pragma unroll
        for (int t = 0; t < NT; t++) {
            const size_t bi = ((size_t)(t * KK + kk) * 64 + lane) * 8;
            bf16x8 bhv = *(const bf16x8*)&Bh[bi];
            bf16x8 blv = *(const bf16x8*)&Bl[bi];
            acc[t] = __builtin_amdgcn_mfma_f32_16x16x32_bf16(ah, bhv, acc[t], 0, 0, 0);
            acc[t] = __builtin_amdgcn_mfma_f32_16x16x32_bf16(al, bhv, acc[t], 0, 0, 0);
            acc[t] = __builtin_amdgcn_mfma_f32_16x16x32_bf16(ah, blv, acc[t], 0, 0, 0);
        }
    }

    const int rowS = blk * 64 + wave * 16 + quad * 4;
#pragma unroll
    for (int t = 0; t < NT; t++) {
#pragma unroll
        for (int r = 0; r < 4; r++) {
            const int rr = rowS + r;
            if (rr < M) out1[(size_t)rr * F1 + head * HID + t * 16 + l16] = acc[t][r];
        }
    }
}

// ---------------------------------------------------------------------------
// Layer-2 aggregation: one wave per dst node, float2/lane (128 ch).
// ---------------------------------------------------------------------------
__global__ __launch_bounds__(256) void agg2_kernel(const int* __restrict__ off,
                                                   const int* __restrict__ col,
                                                   const float* __restrict__ g2,
                                                   const float* __restrict__ as2,
                                                   const float* __restrict__ ad2,
                                                   float* __restrict__ out2, int N) {
    const int w = (blockIdx.x * 256 + threadIdx.x) >> 6;
    const int lane = threadIdx.x & 63;
    if (w >= N) return;
    const float ad = ad2[w];

    float2 acc = make_float2(0.f, 0.f);
    float z = 0.f;
    {
        const float wt = expf(lrelu(as2[w] + ad));
        float2 hv = *(const float2*)&g2[(size_t)w * EMB + lane * 2];
        acc.x += wt * hv.x; acc.y += wt * hv.y;
        z += wt;
    }
    const int jb = off[w], je = off[w + 1];
    int j = jb;
    for (; j + 1 < je; j += 2) {
        const int s0 = col[j], s1 = col[j + 1];
        const float w0 = expf(lrelu(as2[s0] + ad));
        const float w1 = expf(lrelu(as2[s1] + ad));
        float2 v0 = *(const float2*)&g2[(size_t)s0 * EMB + lane * 2];
        float2 v1 = *(const float2*)&g2[(size_t)s1 * EMB + lane * 2];
        acc.x += w0 * v0.x + w1 * v1.x;
        acc.y += w0 * v0.y + w1 * v1.y;
        z += w0 + w1;
    }
    if (j < je) {
        const int s0 = col[j];
        const float w0 = expf(lrelu(as2[s0] + ad));
        float2 v0 = *(const float2*)&g2[(size_t)s0 * EMB + lane * 2];
        acc.x += w0 * v0.x; acc.y += w0 * v0.y;
        z += w0;
    }
    const float inv = 1.f / z;
    float2 o = make_float2(acc.x * inv, acc.y * inv);
    *(float2*)&out2[(size_t)w * EMB + lane * 2] = o;
}

// ---------------------------------------------------------------------------
// Global mean pool: R3 form — 782 blocks, run-length accumulate, rare atomics.
// (R4's 64-block binary-search version was latency-bound at 155 us: 2.5%
//  occupancy. Parallelism > atomic avoidance here.)
// ---------------------------------------------------------------------------
__global__ __launch_bounds__(128) void pool_kernel(const float* __restrict__ out2,
                                                   const float* __restrict__ b2,
                                                   const int* __restrict__ batch,
                                                   float* __restrict__ pool,
                                                   float* __restrict__ cnt, int N) {
    const int c = threadIdx.x;
    const int n0 = blockIdx.x * 64;
    const int nend = min(n0 + 64, N);
    const float bias = b2[c];
    float acc = 0.f, cacc = 0.f;
    int curg = batch[n0];
    for (int n = n0; n < nend; n++) {
        const int g = batch[n];
        if (g != curg) {
            atomicAdd(&pool[curg * EMB + c], acc);
            if (c == 0) atomicAdd(&cnt[curg], cacc);
            acc = 0.f; cacc = 0.f; curg = g;
        }
        float v = out2[(size_t)n * EMB + c] + bias;
        v = v > 0.f ? v : expm1f(v);
        acc += v;
        cacc += 1.f;
    }
    atomicAdd(&pool[curg * EMB + c], acc);
    if (c == 0) atomicAdd(&cnt[curg], cacc);
}

__global__ __launch_bounds__(256) void div_kernel(const float* __restrict__ pool,
                                                  const float* __restrict__ cnt,
                                                  float* __restrict__ out) {
    const int i = blockIdx.x * 256 + threadIdx.x;
    out[i] = pool[i] / fmaxf(cnt[i >> 7], 1.f);
}

// ---------------------------------------------------------------------------
extern "C" void kernel_launch(void* const* d_in, const int* in_sizes, int n_in,
                              void* d_out, int out_size, void* d_ws, size_t ws_size,
                              hipStream_t stream) {
    const float* x      = (const float*)d_in[0];
    const int*   ei     = (const int*)d_in[1];
    const int*   batch  = (const int*)d_in[3];
    const float* W1     = (const float*)d_in[4];
    const float* a_src1 = (const float*)d_in[5];
    const float* a_dst1 = (const float*)d_in[6];
    const float* b1     = (const float*)d_in[7];
    const float* W2     = (const float*)d_in[8];
    const float* a_src2 = (const float*)d_in[9];
    const float* a_dst2 = (const float*)d_in[10];
    const float* b2     = (const float*)d_in[11];
    float* out = (float*)d_out;

    const int N = N_NODES, E = N_EDGES;

    size_t cur_off = 0;
    auto carve = [&](size_t bytes) {
        size_t o = cur_off;
        cur_off = (cur_off + bytes + 255) & ~(size_t)255;
        return (char*)d_ws + o;
    };
    // zero-init region: deg + pool + cnt
    int* deg     = (int*)carve((size_t)N * 4);
    float* pool  = (float*)carve((size_t)N_GRAPHS * EMB * 4);
    float* cnt   = (float*)carve((size_t)N_GRAPHS * 4);
    const size_t zero_bytes = cur_off;
    int* curp    = (int*)carve((size_t)N * 4);
    __bf16* B1h  = (__bf16*)carve((size_t)HEADS * W1_FRAG * 2);
    __bf16* B1l  = (__bf16*)carve((size_t)HEADS * W1_FRAG * 2);
    __bf16* B2h  = (__bf16*)carve((size_t)F1 * EMB * 2);
    __bf16* B2l  = (__bf16*)carve((size_t)F1 * EMB * 2);
    int* off     = (int*)carve((size_t)(N + 1) * 4);
    int* col     = (int*)carve((size_t)E * 4);
    float* aggx  = (float*)carve((size_t)N * HEADS * IN_DIM * 4);  // 102.4 MB
    float* out1  = (float*)carve((size_t)N * F1 * 4);
    float* g2    = (float*)carve((size_t)N * EMB * 4);
    float* out2  = (float*)carve((size_t)N * EMB * 4);
    float* as1   = (float*)carve((size_t)N * HEADS * 4);
    float* ad1   = (float*)carve((size_t)N * HEADS * 4);
    float* as2   = (float*)carve((size_t)N * 4);
    float* ad2   = (float*)carve((size_t)N * 4);

    hipMemsetAsync(d_ws, 0, zero_bytes, stream);

    // deg histogram + weight packs
    prep_kernel<<<DEG_BLOCKS + 32, 256, 0, stream>>>(ei, deg, W1, B1h, B1l, W2, B2h, B2l);
    scan_kernel<<<1, 1024, 0, stream>>>(deg, off, curp, N);

    // gemm1 (x -> as1/ad1 only, no h1 store) + CSR scatter, one dispatch
    gemm1_scatter_kernel<<<GEMM1_BLOCKS + SCAT_BLOCKS, 256, 0, stream>>>(
        x, B1h, B1l, a_src1, a_dst1, as1, ad1, N, ei, off, curp, col);

    // aggregate weighted x per head (gathers 512 B rows instead of 1 KB)
    agg1x_kernel<<<(N + 3) / 4, 256, 0, stream>>>(off, col, x, as1, ad1, aggx, N);

    // out1 = aggx @ W1 (per head), then layer 2
    gemm_bd_kernel<<<dim3((N + 63) / 64, HEADS), 256, 0, stream>>>(aggx, B1h, B1l, out1, N);

    gemm2_kernel<<<(N + 63) / 64, 256, 0, stream>>>(out1, B2h, B2l, b1, a_src2, a_dst2,
                                                    g2, as2, ad2, N);
    agg2_kernel<<<(N + 3) / 4, 256, 0, stream>>>(off, col, g2, as2, ad2, out2, N);

    // pool + divide
    pool_kernel<<<(N + 63) / 64, 128, 0, stream>>>(out2, b2, batch, pool, cnt, N);
    div_kernel<<<(N_GRAPHS * EMB) / 256, 256, 0, stream>>>(pool, cnt, out);
}

// Round 6
// 554.776 us; speedup vs baseline: 1.2586x; 1.0881x over previous
//
#include <hip/hip_runtime.h>
#include <hip/hip_bf16.h>
#include <cstddef>

// Problem constants (fixed-shape problem)
constexpr int N_NODES = 50000;
constexpr int N_EDGES = 800000;
constexpr int IN_DIM  = 128;
constexpr int HID     = 64;
constexpr int HEADS   = 4;
constexpr int F1      = HEADS * HID;  // 256
constexpr int EMB     = 128;
constexpr int N_GRAPHS = 64;

constexpr int DEG_BLOCKS   = (N_EDGES + 255) / 256;  // 3125
constexpr int GEMM1_BLOCKS = (N_NODES + 63) / 64;    // 782
// per-head W1 fragment size (NT=4, KK=4): 4*4*64*8 bf16 elements
constexpr int W1_FRAG = 4 * 4 * 64 * 8;              // 8192

typedef __bf16 bf16x8 __attribute__((ext_vector_type(8)));
typedef float  f32x4  __attribute__((ext_vector_type(4)));

__device__ __forceinline__ float lrelu(float x) { return x > 0.f ? x : 0.2f * x; }
__device__ __forceinline__ float eluf(float x)  { return x > 0.f ? x : expm1f(x); }

// ---------------------------------------------------------------------------
// Pack a [K x 16*NT] submatrix of B (leading dim ld, origin col0) into
// per-lane MFMA B-fragments, split hi/lo bf16.
// ---------------------------------------------------------------------------
__device__ __forceinline__ void pack_frag(const float* __restrict__ B,
                                          __bf16* __restrict__ hi,
                                          __bf16* __restrict__ lo,
                                          int pblk, int NT, int KK, int ld, int col0) {
    const int gid = pblk * 256 + threadIdx.x;
    if (gid >= NT * KK * 64) return;
    const int lane = gid & 63;
    const int rem  = gid >> 6;
    const int kk   = rem % KK;
    const int t    = rem / KK;
    const int n    = col0 + t * 16 + (lane & 15);
    const int k0   = kk * 32 + (lane >> 4) * 8;
#pragma unroll
    for (int j = 0; j < 8; j++) {
        const float v = B[(size_t)(k0 + j) * ld + n];
        const __bf16 h = (__bf16)v;
        hi[(size_t)gid * 8 + j] = h;
        lo[(size_t)gid * 8 + j] = (__bf16)(v - (float)h);
    }
}

// ---------------------------------------------------------------------------
// prep: [deg histogram | pack W1 per-head | pack W2] by block range.
// ---------------------------------------------------------------------------
__global__ __launch_bounds__(256) void prep_kernel(const int* __restrict__ ei,
                                                   int* __restrict__ deg,
                                                   const float* __restrict__ W1,
                                                   __bf16* __restrict__ B1h,
                                                   __bf16* __restrict__ B1l,
                                                   const float* __restrict__ W2,
                                                   __bf16* __restrict__ B2h,
                                                   __bf16* __restrict__ B2l) {
    const int b = blockIdx.x;
    if (b < DEG_BLOCKS) {
        const int e = b * 256 + threadIdx.x;
        if (e < N_EDGES) atomicAdd(&deg[ei[N_EDGES + e]], 1);
        return;
    }
    const int pb = b - DEG_BLOCKS;
    if (pb < 16) {
        const int head = pb >> 2;
        pack_frag(W1, B1h + head * W1_FRAG, B1l + head * W1_FRAG,
                  pb & 3, 4, 4, F1, head * HID);
    } else {
        pack_frag(W2, B2h, B2l, pb - 16, 8, 8, EMB, 0);
    }
}

// ---------------------------------------------------------------------------
// Single-block scan: off = exclusive prefix of deg; also zeroes cur.
// ---------------------------------------------------------------------------
__global__ __launch_bounds__(1024) void scan_kernel(const int* __restrict__ deg,
                                                    int* __restrict__ off,
                                                    int* __restrict__ cur, int N) {
    __shared__ int sums[1024];
    const int t = threadIdx.x;
    const int chunk = (N + 1023) / 1024;
    const int begin = t * chunk;
    const int end = min(begin + chunk, N);
    int s = 0;
    for (int i = begin; i < end; i++) s += deg[i];
    sums[t] = s;
    __syncthreads();
    for (int o = 1; o < 1024; o <<= 1) {
        int v = (t >= o) ? sums[t - o] : 0;
        __syncthreads();
        sums[t] += v;
        __syncthreads();
    }
    int excl = (t == 0) ? 0 : sums[t - 1];
    for (int i = begin; i < end; i++) {
        off[i] = excl;
        cur[i] = 0;
        excl += deg[i];
    }
    if (t == 1023) off[N] = sums[1023];
}

// ---------------------------------------------------------------------------
// Split-bf16 MFMA GEMM (+ optional C store) + fused attention logits.
// ---------------------------------------------------------------------------
template <int NT, int KK, int NH, bool ELU_A, bool STORE_C>
__device__ __forceinline__ void gemm_alpha_body(int blk,
                                                const float* __restrict__ A,
                                                const __bf16* __restrict__ Bh,
                                                const __bf16* __restrict__ Bl,
                                                const float* __restrict__ bias,
                                                const float* __restrict__ avs,
                                                const float* __restrict__ avd,
                                                float* __restrict__ C,
                                                float* __restrict__ as_out,
                                                float* __restrict__ ad_out, int M) {
    constexpr int Ncols = NT * 16;
    constexpr int K = KK * 32;
    const int tid  = threadIdx.x;
    const int wave = tid >> 6, lane = tid & 63;
    const int quad = lane >> 4, l16 = lane & 15;
    const int rowA = min(blk * 64 + wave * 16 + l16, M - 1);

    f32x4 acc[NT];
#pragma unroll
    for (int t = 0; t < NT; t++) acc[t] = (f32x4){0.f, 0.f, 0.f, 0.f};

    for (int kk = 0; kk < KK; kk++) {
        const int k0 = kk * 32 + quad * 8;
        float a8[8];
        *(float4*)&a8[0] = *(const float4*)&A[(size_t)rowA * K + k0];
        *(float4*)&a8[4] = *(const float4*)&A[(size_t)rowA * K + k0 + 4];
        if (ELU_A) {
#pragma unroll
            for (int j = 0; j < 8; j++) a8[j] = eluf(a8[j] + bias[k0 + j]);
        }
        bf16x8 ah, al;
#pragma unroll
        for (int j = 0; j < 8; j++) {
            const __bf16 h = (__bf16)a8[j];
            ah[j] = h;
            al[j] = (__bf16)(a8[j] - (float)h);
        }
#pragma unroll
        for (int t = 0; t < NT; t++) {
            const size_t bi = ((size_t)(t * KK + kk) * 64 + lane) * 8;
            bf16x8 bhv = *(const bf16x8*)&Bh[bi];
            bf16x8 blv = *(const bf16x8*)&Bl[bi];
            acc[t] = __builtin_amdgcn_mfma_f32_16x16x32_bf16(ah, bhv, acc[t], 0, 0, 0);
            acc[t] = __builtin_amdgcn_mfma_f32_16x16x32_bf16(al, bhv, acc[t], 0, 0, 0);
            acc[t] = __builtin_amdgcn_mfma_f32_16x16x32_bf16(ah, blv, acc[t], 0, 0, 0);
        }
    }

    const int rowS = blk * 64 + wave * 16 + quad * 4;
    if (STORE_C) {
#pragma unroll
        for (int t = 0; t < NT; t++) {
#pragma unroll
            for (int r = 0; r < 4; r++) {
                const int rr = rowS + r;
                if (rr < M) C[(size_t)rr * Ncols + t * 16 + l16] = acc[t][r];
            }
        }
    }

#pragma unroll
    for (int r = 0; r < 4; r++) {
        float ps[NH], pd[NH];
#pragma unroll
        for (int h = 0; h < NH; h++) { ps[h] = 0.f; pd[h] = 0.f; }
#pragma unroll
        for (int t = 0; t < NT; t++) {
            const int h = (t * 16) / (Ncols / NH);
            const int col = t * 16 + l16;
            ps[h] += acc[t][r] * avs[col];
            pd[h] += acc[t][r] * avd[col];
        }
#pragma unroll
        for (int o = 1; o < 16; o <<= 1) {
#pragma unroll
            for (int h = 0; h < NH; h++) {
                ps[h] += __shfl_xor(ps[h], o);
                pd[h] += __shfl_xor(pd[h], o);
            }
        }
        const int rr = rowS + r;
        if (l16 == 0 && rr < M) {
#pragma unroll
            for (int h = 0; h < NH; h++) {
                as_out[rr * NH + h] = ps[h];
                ad_out[rr * NH + h] = pd[h];
            }
        }
    }
}

// gemm1 (x -> as1/ad1 only) fused with CSR scatter (writes col AND row).
__global__ __launch_bounds__(256) void gemm1_scatter_kernel(
        const float* __restrict__ A, const __bf16* __restrict__ Bh,
        const __bf16* __restrict__ Bl, const float* __restrict__ avs,
        const float* __restrict__ avd, float* __restrict__ as_out,
        float* __restrict__ ad_out, int M,
        const int* __restrict__ ei, const int* __restrict__ off,
        int* __restrict__ cur, int* __restrict__ col, int* __restrict__ row) {
    if (blockIdx.x < GEMM1_BLOCKS) {
        gemm_alpha_body<F1 / 16, IN_DIM / 32, HEADS, false, false>(
            blockIdx.x, A, Bh, Bl, nullptr, avs, avd, nullptr, as_out, ad_out, M);
        return;
    }
    const int e = (blockIdx.x - GEMM1_BLOCKS) * 256 + threadIdx.x;
    if (e >= N_EDGES) return;
    const int s = ei[e], d = ei[N_EDGES + e];
    const int pos = atomicAdd(&cur[d], 1);
    col[off[d] + pos] = s;
    row[off[d] + pos] = d;
}

__global__ __launch_bounds__(256) void gemm2_kernel(
        const float* __restrict__ A, const __bf16* __restrict__ Bh,
        const __bf16* __restrict__ Bl, const float* __restrict__ bias,
        const float* __restrict__ avs, const float* __restrict__ avd,
        float* __restrict__ C, float* __restrict__ as_out,
        float* __restrict__ ad_out, int M) {
    gemm_alpha_body<EMB / 16, F1 / 32, 1, true, true>(
        blockIdx.x, A, Bh, Bl, bias, avs, avd, C, as_out, ad_out, M);
}

// ---------------------------------------------------------------------------
// Edge-weight kernel: each edge's 4 head-weights computed ONCE (not 64x/wave).
// w4[slot] = exp(lrelu(as1[col[slot]] + ad1[row[slot]]))  (float4 over heads)
// ---------------------------------------------------------------------------
__global__ __launch_bounds__(256) void w1_kernel(const int* __restrict__ col,
                                                 const int* __restrict__ row,
                                                 const float* __restrict__ as1,
                                                 const float* __restrict__ ad1,
                                                 float4* __restrict__ w4, int E) {
    const int i = blockIdx.x * 256 + threadIdx.x;
    if (i >= E) return;
    const int s = col[i], d = row[i];
    const float4 a = *(const float4*)&as1[s * HEADS];
    const float4 b = *(const float4*)&ad1[d * HEADS];
    float4 o;
    o.x = expf(lrelu(a.x + b.x));
    o.y = expf(lrelu(a.y + b.y));
    o.z = expf(lrelu(a.z + b.z));
    o.w = expf(lrelu(a.w + b.w));
    w4[i] = o;
}

// ---------------------------------------------------------------------------
// Layer-1 x-aggregation: one wave per dst node, precomputed weights,
// 4-edge unroll. aggx[node][head][:] = (sum_e w_e x[src_e]) / z_h.
// ---------------------------------------------------------------------------
__global__ __launch_bounds__(256) void agg1x_kernel(const int* __restrict__ off,
                                                    const int* __restrict__ col,
                                                    const float4* __restrict__ w4,
                                                    const float* __restrict__ x,
                                                    const float* __restrict__ as1,
                                                    const float* __restrict__ ad1,
                                                    float* __restrict__ aggx, int N) {
    const int w = (blockIdx.x * 256 + threadIdx.x) >> 6;
    const int lane = threadIdx.x & 63;
    if (w >= N) return;

    float2 acc[HEADS];
    float z[HEADS];
#pragma unroll
    for (int h = 0; h < HEADS; h++) { acc[h] = make_float2(0.f, 0.f); z[h] = 0.f; }

    // self-loop (weights computed inline once per node)
    {
        const float4 asv = *(const float4*)&as1[w * HEADS];
        const float4 adv = *(const float4*)&ad1[w * HEADS];
        const float2 xv = *(const float2*)&x[(size_t)w * IN_DIM + lane * 2];
        float ws[HEADS] = {expf(lrelu(asv.x + adv.x)), expf(lrelu(asv.y + adv.y)),
                           expf(lrelu(asv.z + adv.z)), expf(lrelu(asv.w + adv.w))};
#pragma unroll
        for (int h = 0; h < HEADS; h++) {
            acc[h].x += ws[h] * xv.x; acc[h].y += ws[h] * xv.y; z[h] += ws[h];
        }
    }
    const int jb = off[w], je = off[w + 1];
    int j = jb;
    for (; j + 3 < je; j += 4) {
        const int s0 = col[j], s1 = col[j + 1], s2 = col[j + 2], s3 = col[j + 3];
        const float4 w0 = w4[j], w1 = w4[j + 1], w2 = w4[j + 2], w3 = w4[j + 3];
        const float2 v0 = *(const float2*)&x[(size_t)s0 * IN_DIM + lane * 2];
        const float2 v1 = *(const float2*)&x[(size_t)s1 * IN_DIM + lane * 2];
        const float2 v2 = *(const float2*)&x[(size_t)s2 * IN_DIM + lane * 2];
        const float2 v3 = *(const float2*)&x[(size_t)s3 * IN_DIM + lane * 2];
        acc[0].x += w0.x * v0.x + w1.x * v1.x + w2.x * v2.x + w3.x * v3.x;
        acc[0].y += w0.x * v0.y + w1.x * v1.y + w2.x * v2.y + w3.x * v3.y;
        acc[1].x += w0.y * v0.x + w1.y * v1.x + w2.y * v2.x + w3.y * v3.x;
        acc[1].y += w0.y * v0.y + w1.y * v1.y + w2.y * v2.y + w3.y * v3.y;
        acc[2].x += w0.z * v0.x + w1.z * v1.x + w2.z * v2.x + w3.z * v3.x;
        acc[2].y += w0.z * v0.y + w1.z * v1.y + w2.z * v2.y + w3.z * v3.y;
        acc[3].x += w0.w * v0.x + w1.w * v1.x + w2.w * v2.x + w3.w * v3.x;
        acc[3].y += w0.w * v0.y + w1.w * v1.y + w2.w * v2.y + w3.w * v3.y;
        z[0] += (w0.x + w1.x) + (w2.x + w3.x);
        z[1] += (w0.y + w1.y) + (w2.y + w3.y);
        z[2] += (w0.z + w1.z) + (w2.z + w3.z);
        z[3] += (w0.w + w1.w) + (w2.w + w3.w);
    }
    for (; j < je; j++) {
        const int s0 = col[j];
        const float4 w0 = w4[j];
        const float2 v0 = *(const float2*)&x[(size_t)s0 * IN_DIM + lane * 2];
        acc[0].x += w0.x * v0.x; acc[0].y += w0.x * v0.y; z[0] += w0.x;
        acc[1].x += w0.y * v0.x; acc[1].y += w0.y * v0.y; z[1] += w0.y;
        acc[2].x += w0.z * v0.x; acc[2].y += w0.z * v0.y; z[2] += w0.z;
        acc[3].x += w0.w * v0.x; acc[3].y += w0.w * v0.y; z[3] += w0.w;
    }
#pragma unroll
    for (int h = 0; h < HEADS; h++) {
        const float inv = 1.f / z[h];
        float2 o = make_float2(acc[h].x * inv, acc[h].y * inv);
        *(float2*)&aggx[((size_t)w * HEADS + h) * IN_DIM + lane * 2] = o;
    }
}

// ---------------------------------------------------------------------------
// Head-GEMM: out1[:, h*64:(h+1)*64] = aggx[:, h, :] @ W1[:, h*64:(h+1)*64]
// ---------------------------------------------------------------------------
__global__ __launch_bounds__(256) void gemm_bd_kernel(const float* __restrict__ aggx,
                                                      const __bf16* __restrict__ B1h,
                                                      const __bf16* __restrict__ B1l,
                                                      float* __restrict__ out1, int M) {
    constexpr int NT = 4, KK = 4;
    const int head = blockIdx.y;
    const int blk = blockIdx.x;
    const int tid  = threadIdx.x;
    const int wave = tid >> 6, lane = tid & 63;
    const int quad = lane >> 4, l16 = lane & 15;
    const int rowA = min(blk * 64 + wave * 16 + l16, M - 1);
    const float* Arow = aggx + ((size_t)rowA * HEADS + head) * IN_DIM;
    const __bf16* Bh = B1h + head * W1_FRAG;
    const __bf16* Bl = B1l + head * W1_FRAG;

    f32x4 acc[NT];
#pragma unroll
    for (int t = 0; t < NT; t++) acc[t] = (f32x4){0.f, 0.f, 0.f, 0.f};

    for (int kk = 0; kk < KK; kk++) {
        const int k0 = kk * 32 + quad * 8;
        float a8[8];
        *(float4*)&a8[0] = *(const float4*)&Arow[k0];
        *(float4*)&a8[4] = *(const float4*)&Arow[k0 + 4];
        bf16x8 ah, al;
#pragma unroll
        for (int j = 0; j < 8; j++) {
            const __bf16 h = (__bf16)a8[j];
            ah[j] = h;
            al[j] = (__bf16)(a8[j] - (float)h);
        }
#pragma unroll
        for (int t = 0; t < NT; t++) {
            const size_t bi = ((size_t)(t * KK + kk) * 64 + lane) * 8;
            bf16x8 bhv = *(const bf16x8*)&Bh[bi];
            bf16x8 blv = *(const bf16x8*)&Bl[bi];
            acc[t] = __builtin_amdgcn_mfma_f32_16x16x32_bf16(ah, bhv, acc[t], 0, 0, 0);
            acc[t] = __builtin_amdgcn_mfma_f32_16x16x32_bf16(al, bhv, acc[t], 0, 0, 0);
            acc[t] = __builtin_amdgcn_mfma_f32_16x16x32_bf16(ah, blv, acc[t], 0, 0, 0);
        }
    }

    const int rowS = blk * 64 + wave * 16 + quad * 4;
#pragma unroll
    for (int t = 0; t < NT; t++) {
#pragma unroll
        for (int r = 0; r < 4; r++) {
            const int rr = rowS + r;
            if (rr < M) out1[(size_t)rr * F1 + head * HID + t * 16 + l16] = acc[t][r];
        }
    }
}

// ---------------------------------------------------------------------------
// Layer-2 aggregation: one wave per dst node, inline exp (1 head), 4-unroll.
// ---------------------------------------------------------------------------
__global__ __launch_bounds__(256) void agg2_kernel(const int* __restrict__ off,
                                                   const int* __restrict__ col,
                                                   const float* __restrict__ g2,
                                                   const float* __restrict__ as2,
                                                   const float* __restrict__ ad2,
                                                   float* __restrict__ out2, int N) {
    const int w = (blockIdx.x * 256 + threadIdx.x) >> 6;
    const int lane = threadIdx.x & 63;
    if (w >= N) return;
    const float ad = ad2[w];

    float2 acc = make_float2(0.f, 0.f);
    float z = 0.f;
    {
        const float wt = expf(lrelu(as2[w] + ad));
        float2 hv = *(const float2*)&g2[(size_t)w * EMB + lane * 2];
        acc.x += wt * hv.x; acc.y += wt * hv.y;
        z += wt;
    }
    const int jb = off[w], je = off[w + 1];
    int j = jb;
    for (; j + 3 < je; j += 4) {
        const int s0 = col[j], s1 = col[j + 1], s2 = col[j + 2], s3 = col[j + 3];
        const float w0 = expf(lrelu(as2[s0] + ad));
        const float w1 = expf(lrelu(as2[s1] + ad));
        const float w2 = expf(lrelu(as2[s2] + ad));
        const float w3 = expf(lrelu(as2[s3] + ad));
        const float2 v0 = *(const float2*)&g2[(size_t)s0 * EMB + lane * 2];
        const float2 v1 = *(const float2*)&g2[(size_t)s1 * EMB + lane * 2];
        const float2 v2 = *(const float2*)&g2[(size_t)s2 * EMB + lane * 2];
        const float2 v3 = *(const float2*)&g2[(size_t)s3 * EMB + lane * 2];
        acc.x += w0 * v0.x + w1 * v1.x + w2 * v2.x + w3 * v3.x;
        acc.y += w0 * v0.y + w1 * v1.y + w2 * v2.y + w3 * v3.y;
        z += (w0 + w1) + (w2 + w3);
    }
    for (; j < je; j++) {
        const int s0 = col[j];
        const float w0 = expf(lrelu(as2[s0] + ad));
        const float2 v0 = *(const float2*)&g2[(size_t)s0 * EMB + lane * 2];
        acc.x += w0 * v0.x; acc.y += w0 * v0.y;
        z += w0;
    }
    const float inv = 1.f / z;
    float2 o = make_float2(acc.x * inv, acc.y * inv);
    *(float2*)&out2[(size_t)w * EMB + lane * 2] = o;
}

// ---------------------------------------------------------------------------
// Global mean pool (782-block run-length form; R4's 64-block version was
// latency-bound at 2.5% occupancy — parallelism > atomic avoidance here).
// ---------------------------------------------------------------------------
__global__ __launch_bounds__(128) void pool_kernel(const float* __restrict__ out2,
                                                   const float* __restrict__ b2,
                                                   const int* __restrict__ batch,
                                                   float* __restrict__ pool,
                                                   float* __restrict__ cnt, int N) {
    const int c = threadIdx.x;
    const int n0 = blockIdx.x * 64;
    const int nend = min(n0 + 64, N);
    const float bias = b2[c];
    float acc = 0.f, cacc = 0.f;
    int curg = batch[n0];
    for (int n = n0; n < nend; n++) {
        const int g = batch[n];
        if (g != curg) {
            atomicAdd(&pool[curg * EMB + c], acc);
            if (c == 0) atomicAdd(&cnt[curg], cacc);
            acc = 0.f; cacc = 0.f; curg = g;
        }
        float v = out2[(size_t)n * EMB + c] + bias;
        v = v > 0.f ? v : expm1f(v);
        acc += v;
        cacc += 1.f;
    }
    atomicAdd(&pool[curg * EMB + c], acc);
    if (c == 0) atomicAdd(&cnt[curg], cacc);
}

__global__ __launch_bounds__(256) void div_kernel(const float* __restrict__ pool,
                                                  const float* __restrict__ cnt,
                                                  float* __restrict__ out) {
    const int i = blockIdx.x * 256 + threadIdx.x;
    out[i] = pool[i] / fmaxf(cnt[i >> 7], 1.f);
}

// ---------------------------------------------------------------------------
extern "C" void kernel_launch(void* const* d_in, const int* in_sizes, int n_in,
                              void* d_out, int out_size, void* d_ws, size_t ws_size,
                              hipStream_t stream) {
    const float* x      = (const float*)d_in[0];
    const int*   ei     = (const int*)d_in[1];
    const int*   batch  = (const int*)d_in[3];
    const float* W1     = (const float*)d_in[4];
    const float* a_src1 = (const float*)d_in[5];
    const float* a_dst1 = (const float*)d_in[6];
    const float* b1     = (const float*)d_in[7];
    const float* W2     = (const float*)d_in[8];
    const float* a_src2 = (const float*)d_in[9];
    const float* a_dst2 = (const float*)d_in[10];
    const float* b2     = (const float*)d_in[11];
    float* out = (float*)d_out;

    const int N = N_NODES, E = N_EDGES;

    size_t cur_off = 0;
    auto carve = [&](size_t bytes) {
        size_t o = cur_off;
        cur_off = (cur_off + bytes + 255) & ~(size_t)255;
        return (char*)d_ws + o;
    };
    // zero-init region: deg + pool + cnt
    int* deg     = (int*)carve((size_t)N * 4);
    float* pool  = (float*)carve((size_t)N_GRAPHS * EMB * 4);
    float* cnt   = (float*)carve((size_t)N_GRAPHS * 4);
    const size_t zero_bytes = cur_off;
    int* curp    = (int*)carve((size_t)N * 4);
    __bf16* B1h  = (__bf16*)carve((size_t)HEADS * W1_FRAG * 2);
    __bf16* B1l  = (__bf16*)carve((size_t)HEADS * W1_FRAG * 2);
    __bf16* B2h  = (__bf16*)carve((size_t)F1 * EMB * 2);
    __bf16* B2l  = (__bf16*)carve((size_t)F1 * EMB * 2);
    int* off     = (int*)carve((size_t)(N + 1) * 4);
    int* col     = (int*)carve((size_t)E * 4);
    int* rowd    = (int*)carve((size_t)E * 4);
    float4* w4   = (float4*)carve((size_t)E * 16);
    float* aggx  = (float*)carve((size_t)N * HEADS * IN_DIM * 4);
    float* out1  = (float*)carve((size_t)N * F1 * 4);
    float* g2    = (float*)carve((size_t)N * EMB * 4);
    float* out2  = (float*)carve((size_t)N * EMB * 4);
    float* as1   = (float*)carve((size_t)N * HEADS * 4);
    float* ad1   = (float*)carve((size_t)N * HEADS * 4);
    float* as2   = (float*)carve((size_t)N * 4);
    float* ad2   = (float*)carve((size_t)N * 4);

    hipMemsetAsync(d_ws, 0, zero_bytes, stream);

    prep_kernel<<<DEG_BLOCKS + 32, 256, 0, stream>>>(ei, deg, W1, B1h, B1l, W2, B2h, B2l);
    scan_kernel<<<1, 1024, 0, stream>>>(deg, off, curp, N);

    // gemm1 (x -> as1/ad1) + CSR scatter (col/row), one dispatch
    gemm1_scatter_kernel<<<GEMM1_BLOCKS + DEG_BLOCKS, 256, 0, stream>>>(
        x, B1h, B1l, a_src1, a_dst1, as1, ad1, N, ei, off, curp, col, rowd);

    // per-edge head weights, computed once per edge
    w1_kernel<<<(E + 255) / 256, 256, 0, stream>>>(col, rowd, as1, ad1, w4, E);

    agg1x_kernel<<<(N + 3) / 4, 256, 0, stream>>>(off, col, w4, x, as1, ad1, aggx, N);

    gemm_bd_kernel<<<dim3((N + 63) / 64, HEADS), 256, 0, stream>>>(aggx, B1h, B1l, out1, N);

    gemm2_kernel<<<(N + 63) / 64, 256, 0, stream>>>(out1, B2h, B2l, b1, a_src2, a_dst2,
                                                    g2, as2, ad2, N);
    agg2_kernel<<<(N + 3) / 4, 256, 0, stream>>>(off, col, g2, as2, ad2, out2, N);

    pool_kernel<<<(N + 63) / 64, 128, 0, stream>>>(out2, b2, batch, pool, cnt, N);
    div_kernel<<<(N_GRAPHS * EMB) / 256, 256, 0, stream>>>(pool, cnt, out);
}

// Round 7
// 456.486 us; speedup vs baseline: 1.5296x; 1.2153x over previous
//
#include <hip/hip_runtime.h>
#include <hip/hip_bf16.h>
#include <cstddef>

// Problem constants (fixed-shape problem)
constexpr int N_NODES = 50000;
constexpr int N_EDGES = 800000;
constexpr int IN_DIM  = 128;
constexpr int HID     = 64;
constexpr int HEADS   = 4;
constexpr int F1      = HEADS * HID;  // 256
constexpr int EMB     = 128;
constexpr int N_GRAPHS = 64;

constexpr int DEG_BLOCKS   = (N_EDGES + 255) / 256;  // 3125
constexpr int GEMM1_BLOCKS = (N_NODES + 63) / 64;    // 782
constexpr int SCAN_BLOCKS  = (N_NODES + 255) / 256;  // 196
// per-head W1 fragment size (NT=4, KK=4): 4*4*64*8 bf16 elements
constexpr int W1_FRAG = 4 * 4 * 64 * 8;              // 8192

typedef __bf16 bf16x8 __attribute__((ext_vector_type(8)));
typedef float  f32x4  __attribute__((ext_vector_type(4)));

__device__ __forceinline__ float lrelu(float x) { return x > 0.f ? x : 0.2f * x; }
__device__ __forceinline__ float eluf(float x)  { return x > 0.f ? x : expm1f(x); }

// ---------------------------------------------------------------------------
// Pack a [K x 16*NT] submatrix of B (leading dim ld, origin col0) into
// per-lane MFMA B-fragments, split hi/lo bf16.
// ---------------------------------------------------------------------------
__device__ __forceinline__ void pack_frag(const float* __restrict__ B,
                                          __bf16* __restrict__ hi,
                                          __bf16* __restrict__ lo,
                                          int pblk, int NT, int KK, int ld, int col0) {
    const int gid = pblk * 256 + threadIdx.x;
    if (gid >= NT * KK * 64) return;
    const int lane = gid & 63;
    const int rem  = gid >> 6;
    const int kk   = rem % KK;
    const int t    = rem / KK;
    const int n    = col0 + t * 16 + (lane & 15);
    const int k0   = kk * 32 + (lane >> 4) * 8;
#pragma unroll
    for (int j = 0; j < 8; j++) {
        const float v = B[(size_t)(k0 + j) * ld + n];
        const __bf16 h = (__bf16)v;
        hi[(size_t)gid * 8 + j] = h;
        lo[(size_t)gid * 8 + j] = (__bf16)(v - (float)h);
    }
}

// ---------------------------------------------------------------------------
// prep: [deg histogram | pack W1 per-head | pack W2] by block range.
// ---------------------------------------------------------------------------
__global__ __launch_bounds__(256) void prep_kernel(const int* __restrict__ ei,
                                                   int* __restrict__ deg,
                                                   const float* __restrict__ W1,
                                                   __bf16* __restrict__ B1h,
                                                   __bf16* __restrict__ B1l,
                                                   const float* __restrict__ W2,
                                                   __bf16* __restrict__ B2h,
                                                   __bf16* __restrict__ B2l) {
    const int b = blockIdx.x;
    if (b < DEG_BLOCKS) {
        const int e = b * 256 + threadIdx.x;
        if (e < N_EDGES) atomicAdd(&deg[ei[N_EDGES + e]], 1);
        return;
    }
    const int pb = b - DEG_BLOCKS;
    if (pb < 16) {
        const int head = pb >> 2;
        pack_frag(W1, B1h + head * W1_FRAG, B1l + head * W1_FRAG,
                  pb & 3, 4, 4, F1, head * HID);
    } else {
        pack_frag(W2, B2h, B2l, pb - 16, 8, 8, EMB, 0);
    }
}

// ---------------------------------------------------------------------------
// 3-phase parallel scan (replaces R6's 1-block scan: 113 us at 0.14%
// occupancy, latency-bound. Parallelism > single-pass cleverness.)
// A: per-block LDS scan -> intra-block exclusive prefix + block totals
// B: 1 block scans the 196 block totals -> exclusive bases, writes off[N]
// C: add bases, zero cur
// ---------------------------------------------------------------------------
__global__ __launch_bounds__(256) void scanA_kernel(const int* __restrict__ deg,
                                                    int* __restrict__ off,
                                                    int* __restrict__ partial, int N) {
    __shared__ int sm[256];
    const int t = threadIdx.x;
    const int i = blockIdx.x * 256 + t;
    const int v = (i < N) ? deg[i] : 0;
    sm[t] = v;
    __syncthreads();
    int val = v;
#pragma unroll
    for (int o = 1; o < 256; o <<= 1) {
        const int add = (t >= o) ? sm[t - o] : 0;
        __syncthreads();
        val += add;
        sm[t] = val;
        __syncthreads();
    }
    if (i < N) off[i] = val - v;  // intra-block exclusive prefix
    if (t == 255) partial[blockIdx.x] = val;  // block total
}

__global__ __launch_bounds__(256) void scanB_kernel(int* __restrict__ partial,
                                                    int* __restrict__ off_last) {
    __shared__ int sm[256];
    const int t = threadIdx.x;
    const int v = (t < SCAN_BLOCKS) ? partial[t] : 0;
    sm[t] = v;
    __syncthreads();
    int val = v;
#pragma unroll
    for (int o = 1; o < 256; o <<= 1) {
        const int add = (t >= o) ? sm[t - o] : 0;
        __syncthreads();
        val += add;
        sm[t] = val;
        __syncthreads();
    }
    if (t < SCAN_BLOCKS) partial[t] = val - v;  // exclusive base per block
    if (t == SCAN_BLOCKS - 1) *off_last = val;  // grand total -> off[N]
}

__global__ __launch_bounds__(256) void scanC_kernel(int* __restrict__ off,
                                                    const int* __restrict__ partial,
                                                    int* __restrict__ cur, int N) {
    const int i = blockIdx.x * 256 + threadIdx.x;
    if (i < N) {
        off[i] += partial[blockIdx.x];
        cur[i] = 0;
    }
}

// ---------------------------------------------------------------------------
// Split-bf16 MFMA GEMM (+ optional C store) + fused attention logits.
// ---------------------------------------------------------------------------
template <int NT, int KK, int NH, bool ELU_A, bool STORE_C>
__device__ __forceinline__ void gemm_alpha_body(int blk,
                                                const float* __restrict__ A,
                                                const __bf16* __restrict__ Bh,
                                                const __bf16* __restrict__ Bl,
                                                const float* __restrict__ bias,
                                                const float* __restrict__ avs,
                                                const float* __restrict__ avd,
                                                float* __restrict__ C,
                                                float* __restrict__ as_out,
                                                float* __restrict__ ad_out, int M) {
    constexpr int Ncols = NT * 16;
    constexpr int K = KK * 32;
    const int tid  = threadIdx.x;
    const int wave = tid >> 6, lane = tid & 63;
    const int quad = lane >> 4, l16 = lane & 15;
    const int rowA = min(blk * 64 + wave * 16 + l16, M - 1);

    f32x4 acc[NT];
#pragma unroll
    for (int t = 0; t < NT; t++) acc[t] = (f32x4){0.f, 0.f, 0.f, 0.f};

    for (int kk = 0; kk < KK; kk++) {
        const int k0 = kk * 32 + quad * 8;
        float a8[8];
        *(float4*)&a8[0] = *(const float4*)&A[(size_t)rowA * K + k0];
        *(float4*)&a8[4] = *(const float4*)&A[(size_t)rowA * K + k0 + 4];
        if (ELU_A) {
#pragma unroll
            for (int j = 0; j < 8; j++) a8[j] = eluf(a8[j] + bias[k0 + j]);
        }
        bf16x8 ah, al;
#pragma unroll
        for (int j = 0; j < 8; j++) {
            const __bf16 h = (__bf16)a8[j];
            ah[j] = h;
            al[j] = (__bf16)(a8[j] - (float)h);
        }
#pragma unroll
        for (int t = 0; t < NT; t++) {
            const size_t bi = ((size_t)(t * KK + kk) * 64 + lane) * 8;
            bf16x8 bhv = *(const bf16x8*)&Bh[bi];
            bf16x8 blv = *(const bf16x8*)&Bl[bi];
            acc[t] = __builtin_amdgcn_mfma_f32_16x16x32_bf16(ah, bhv, acc[t], 0, 0, 0);
            acc[t] = __builtin_amdgcn_mfma_f32_16x16x32_bf16(al, bhv, acc[t], 0, 0, 0);
            acc[t] = __builtin_amdgcn_mfma_f32_16x16x32_bf16(ah, blv, acc[t], 0, 0, 0);
        }
    }

    const int rowS = blk * 64 + wave * 16 + quad * 4;
    if (STORE_C) {
#pragma unroll
        for (int t = 0; t < NT; t++) {
#pragma unroll
            for (int r = 0; r < 4; r++) {
                const int rr = rowS + r;
                if (rr < M) C[(size_t)rr * Ncols + t * 16 + l16] = acc[t][r];
            }
        }
    }

#pragma unroll
    for (int r = 0; r < 4; r++) {
        float ps[NH], pd[NH];
#pragma unroll
        for (int h = 0; h < NH; h++) { ps[h] = 0.f; pd[h] = 0.f; }
#pragma unroll
        for (int t = 0; t < NT; t++) {
            const int h = (t * 16) / (Ncols / NH);
            const int col = t * 16 + l16;
            ps[h] += acc[t][r] * avs[col];
            pd[h] += acc[t][r] * avd[col];
        }
#pragma unroll
        for (int o = 1; o < 16; o <<= 1) {
#pragma unroll
            for (int h = 0; h < NH; h++) {
                ps[h] += __shfl_xor(ps[h], o);
                pd[h] += __shfl_xor(pd[h], o);
            }
        }
        const int rr = rowS + r;
        if (l16 == 0 && rr < M) {
#pragma unroll
            for (int h = 0; h < NH; h++) {
                as_out[rr * NH + h] = ps[h];
                ad_out[rr * NH + h] = pd[h];
            }
        }
    }
}

// gemm1 (x -> as1/ad1 only) fused with CSR scatter (writes col AND row).
__global__ __launch_bounds__(256) void gemm1_scatter_kernel(
        const float* __restrict__ A, const __bf16* __restrict__ Bh,
        const __bf16* __restrict__ Bl, const float* __restrict__ avs,
        const float* __restrict__ avd, float* __restrict__ as_out,
        float* __restrict__ ad_out, int M,
        const int* __restrict__ ei, const int* __restrict__ off,
        int* __restrict__ cur, int* __restrict__ col, int* __restrict__ row) {
    if (blockIdx.x < GEMM1_BLOCKS) {
        gemm_alpha_body<F1 / 16, IN_DIM / 32, HEADS, false, false>(
            blockIdx.x, A, Bh, Bl, nullptr, avs, avd, nullptr, as_out, ad_out, M);
        return;
    }
    const int e = (blockIdx.x - GEMM1_BLOCKS) * 256 + threadIdx.x;
    if (e >= N_EDGES) return;
    const int s = ei[e], d = ei[N_EDGES + e];
    const int pos = atomicAdd(&cur[d], 1);
    col[off[d] + pos] = s;
    row[off[d] + pos] = d;
}

__global__ __launch_bounds__(256) void gemm2_kernel(
        const float* __restrict__ A, const __bf16* __restrict__ Bh,
        const __bf16* __restrict__ Bl, const float* __restrict__ bias,
        const float* __restrict__ avs, const float* __restrict__ avd,
        float* __restrict__ C, float* __restrict__ as_out,
        float* __restrict__ ad_out, int M) {
    gemm_alpha_body<EMB / 16, F1 / 32, 1, true, true>(
        blockIdx.x, A, Bh, Bl, bias, avs, avd, C, as_out, ad_out, M);
}

// ---------------------------------------------------------------------------
// Edge-weight kernel: each edge's 4 head-weights computed ONCE (not 64x/wave).
// ---------------------------------------------------------------------------
__global__ __launch_bounds__(256) void w1_kernel(const int* __restrict__ col,
                                                 const int* __restrict__ row,
                                                 const float* __restrict__ as1,
                                                 const float* __restrict__ ad1,
                                                 float4* __restrict__ w4, int E) {
    const int i = blockIdx.x * 256 + threadIdx.x;
    if (i >= E) return;
    const int s = col[i], d = row[i];
    const float4 a = *(const float4*)&as1[s * HEADS];
    const float4 b = *(const float4*)&ad1[d * HEADS];
    float4 o;
    o.x = expf(lrelu(a.x + b.x));
    o.y = expf(lrelu(a.y + b.y));
    o.z = expf(lrelu(a.z + b.z));
    o.w = expf(lrelu(a.w + b.w));
    w4[i] = o;
}

// ---------------------------------------------------------------------------
// Layer-1 x-aggregation: one wave per dst node, precomputed weights,
// 4-edge unroll. aggx[node][head][:] = (sum_e w_e x[src_e]) / z_h.
// ---------------------------------------------------------------------------
__global__ __launch_bounds__(256) void agg1x_kernel(const int* __restrict__ off,
                                                    const int* __restrict__ col,
                                                    const float4* __restrict__ w4,
                                                    const float* __restrict__ x,
                                                    const float* __restrict__ as1,
                                                    const float* __restrict__ ad1,
                                                    float* __restrict__ aggx, int N) {
    const int w = (blockIdx.x * 256 + threadIdx.x) >> 6;
    const int lane = threadIdx.x & 63;
    if (w >= N) return;

    float2 acc[HEADS];
    float z[HEADS];
#pragma unroll
    for (int h = 0; h < HEADS; h++) { acc[h] = make_float2(0.f, 0.f); z[h] = 0.f; }

    {
        const float4 asv = *(const float4*)&as1[w * HEADS];
        const float4 adv = *(const float4*)&ad1[w * HEADS];
        const float2 xv = *(const float2*)&x[(size_t)w * IN_DIM + lane * 2];
        float ws[HEADS] = {expf(lrelu(asv.x + adv.x)), expf(lrelu(asv.y + adv.y)),
                           expf(lrelu(asv.z + adv.z)), expf(lrelu(asv.w + adv.w))};
#pragma unroll
        for (int h = 0; h < HEADS; h++) {
            acc[h].x += ws[h] * xv.x; acc[h].y += ws[h] * xv.y; z[h] += ws[h];
        }
    }
    const int jb = off[w], je = off[w + 1];
    int j = jb;
    for (; j + 3 < je; j += 4) {
        const int s0 = col[j], s1 = col[j + 1], s2 = col[j + 2], s3 = col[j + 3];
        const float4 w0 = w4[j], w1 = w4[j + 1], w2 = w4[j + 2], w3 = w4[j + 3];
        const float2 v0 = *(const float2*)&x[(size_t)s0 * IN_DIM + lane * 2];
        const float2 v1 = *(const float2*)&x[(size_t)s1 * IN_DIM + lane * 2];
        const float2 v2 = *(const float2*)&x[(size_t)s2 * IN_DIM + lane * 2];
        const float2 v3 = *(const float2*)&x[(size_t)s3 * IN_DIM + lane * 2];
        acc[0].x += w0.x * v0.x + w1.x * v1.x + w2.x * v2.x + w3.x * v3.x;
        acc[0].y += w0.x * v0.y + w1.x * v1.y + w2.x * v2.y + w3.x * v3.y;
        acc[1].x += w0.y * v0.x + w1.y * v1.x + w2.y * v2.x + w3.y * v3.x;
        acc[1].y += w0.y * v0.y + w1.y * v1.y + w2.y * v2.y + w3.y * v3.y;
        acc[2].x += w0.z * v0.x + w1.z * v1.x + w2.z * v2.x + w3.z * v3.x;
        acc[2].y += w0.z * v0.y + w1.z * v1.y + w2.z * v2.y + w3.z * v3.y;
        acc[3].x += w0.w * v0.x + w1.w * v1.x + w2.w * v2.x + w3.w * v3.x;
        acc[3].y += w0.w * v0.y + w1.w * v1.y + w2.w * v2.y + w3.w * v3.y;
        z[0] += (w0.x + w1.x) + (w2.x + w3.x);
        z[1] += (w0.y + w1.y) + (w2.y + w3.y);
        z[2] += (w0.z + w1.z) + (w2.z + w3.z);
        z[3] += (w0.w + w1.w) + (w2.w + w3.w);
    }
    for (; j < je; j++) {
        const int s0 = col[j];
        const float4 w0 = w4[j];
        const float2 v0 = *(const float2*)&x[(size_t)s0 * IN_DIM + lane * 2];
        acc[0].x += w0.x * v0.x; acc[0].y += w0.x * v0.y; z[0] += w0.x;
        acc[1].x += w0.y * v0.x; acc[1].y += w0.y * v0.y; z[1] += w0.y;
        acc[2].x += w0.z * v0.x; acc[2].y += w0.z * v0.y; z[2] += w0.z;
        acc[3].x += w0.w * v0.x; acc[3].y += w0.w * v0.y; z[3] += w0.w;
    }
#pragma unroll
    for (int h = 0; h < HEADS; h++) {
        const float inv = 1.f / z[h];
        float2 o = make_float2(acc[h].x * inv, acc[h].y * inv);
        *(float2*)&aggx[((size_t)w * HEADS + h) * IN_DIM + lane * 2] = o;
    }
}

// ---------------------------------------------------------------------------
// Head-GEMM: out1[:, h*64:(h+1)*64] = aggx[:, h, :] @ W1[:, h*64:(h+1)*64]
// ---------------------------------------------------------------------------
__global__ __launch_bounds__(256) void gemm_bd_kernel(const float* __restrict__ aggx,
                                                      const __bf16* __restrict__ B1h,
                                                      const __bf16* __restrict__ B1l,
                                                      float* __restrict__ out1, int M) {
    constexpr int NT = 4, KK = 4;
    const int head = blockIdx.y;
    const int blk = blockIdx.x;
    const int tid  = threadIdx.x;
    const int wave = tid >> 6, lane = tid & 63;
    const int quad = lane >> 4, l16 = lane & 15;
    const int rowA = min(blk * 64 + wave * 16 + l16, M - 1);
    const float* Arow = aggx + ((size_t)rowA * HEADS + head) * IN_DIM;
    const __bf16* Bh = B1h + head * W1_FRAG;
    const __bf16* Bl = B1l + head * W1_FRAG;

    f32x4 acc[NT];
#pragma unroll
    for (int t = 0; t < NT; t++) acc[t] = (f32x4){0.f, 0.f, 0.f, 0.f};

    for (int kk = 0; kk < KK; kk++) {
        const int k0 = kk * 32 + quad * 8;
        float a8[8];
        *(float4*)&a8[0] = *(const float4*)&Arow[k0];
        *(float4*)&a8[4] = *(const float4*)&Arow[k0 + 4];
        bf16x8 ah, al;
#pragma unroll
        for (int j = 0; j < 8; j++) {
            const __bf16 h = (__bf16)a8[j];
            ah[j] = h;
            al[j] = (__bf16)(a8[j] - (float)h);
        }
#pragma unroll
        for (int t = 0; t < NT; t++) {
            const size_t bi = ((size_t)(t * KK + kk) * 64 + lane) * 8;
            bf16x8 bhv = *(const bf16x8*)&Bh[bi];
            bf16x8 blv = *(const bf16x8*)&Bl[bi];
            acc[t] = __builtin_amdgcn_mfma_f32_16x16x32_bf16(ah, bhv, acc[t], 0, 0, 0);
            acc[t] = __builtin_amdgcn_mfma_f32_16x16x32_bf16(al, bhv, acc[t], 0, 0, 0);
            acc[t] = __builtin_amdgcn_mfma_f32_16x16x32_bf16(ah, blv, acc[t], 0, 0, 0);
        }
    }

    const int rowS = blk * 64 + wave * 16 + quad * 4;
#pragma unroll
    for (int t = 0; t < NT; t++) {
#pragma unroll
        for (int r = 0; r < 4; r++) {
            const int rr = rowS + r;
            if (rr < M) out1[(size_t)rr * F1 + head * HID + t * 16 + l16] = acc[t][r];
        }
    }
}

// ---------------------------------------------------------------------------
// Layer-2 aggregation: one wave per dst node, inline exp (1 head), 4-unroll.
// ---------------------------------------------------------------------------
__global__ __launch_bounds__(256) void agg2_kernel(const int* __restrict__ off,
                                                   const int* __restrict__ col,
                                                   const float* __restrict__ g2,
                                                   const float* __restrict__ as2,
                                                   const float* __restrict__ ad2,
                                                   float* __restrict__ out2, int N) {
    const int w = (blockIdx.x * 256 + threadIdx.x) >> 6;
    const int lane = threadIdx.x & 63;
    if (w >= N) return;
    const float ad = ad2[w];

    float2 acc = make_float2(0.f, 0.f);
    float z = 0.f;
    {
        const float wt = expf(lrelu(as2[w] + ad));
        float2 hv = *(const float2*)&g2[(size_t)w * EMB + lane * 2];
        acc.x += wt * hv.x; acc.y += wt * hv.y;
        z += wt;
    }
    const int jb = off[w], je = off[w + 1];
    int j = jb;
    for (; j + 3 < je; j += 4) {
        const int s0 = col[j], s1 = col[j + 1], s2 = col[j + 2], s3 = col[j + 3];
        const float w0 = expf(lrelu(as2[s0] + ad));
        const float w1 = expf(lrelu(as2[s1] + ad));
        const float w2 = expf(lrelu(as2[s2] + ad));
        const float w3 = expf(lrelu(as2[s3] + ad));
        const float2 v0 = *(const float2*)&g2[(size_t)s0 * EMB + lane * 2];
        const float2 v1 = *(const float2*)&g2[(size_t)s1 * EMB + lane * 2];
        const float2 v2 = *(const float2*)&g2[(size_t)s2 * EMB + lane * 2];
        const float2 v3 = *(const float2*)&g2[(size_t)s3 * EMB + lane * 2];
        acc.x += w0 * v0.x + w1 * v1.x + w2 * v2.x + w3 * v3.x;
        acc.y += w0 * v0.y + w1 * v1.y + w2 * v2.y + w3 * v3.y;
        z += (w0 + w1) + (w2 + w3);
    }
    for (; j < je; j++) {
        const int s0 = col[j];
        const float w0 = expf(lrelu(as2[s0] + ad));
        const float2 v0 = *(const float2*)&g2[(size_t)s0 * EMB + lane * 2];
        acc.x += w0 * v0.x; acc.y += w0 * v0.y;
        z += w0;
    }
    const float inv = 1.f / z;
    float2 o = make_float2(acc.x * inv, acc.y * inv);
    *(float2*)&out2[(size_t)w * EMB + lane * 2] = o;
}

// ---------------------------------------------------------------------------
// Global mean pool (782-block run-length form) + divide.
// ---------------------------------------------------------------------------
__global__ __launch_bounds__(128) void pool_kernel(const float* __restrict__ out2,
                                                   const float* __restrict__ b2,
                                                   const int* __restrict__ batch,
                                                   float* __restrict__ pool,
                                                   float* __restrict__ cnt, int N) {
    const int c = threadIdx.x;
    const int n0 = blockIdx.x * 64;
    const int nend = min(n0 + 64, N);
    const float bias = b2[c];
    float acc = 0.f, cacc = 0.f;
    int curg = batch[n0];
    for (int n = n0; n < nend; n++) {
        const int g = batch[n];
        if (g != curg) {
            atomicAdd(&pool[curg * EMB + c], acc);
            if (c == 0) atomicAdd(&cnt[curg], cacc);
            acc = 0.f; cacc = 0.f; curg = g;
        }
        float v = out2[(size_t)n * EMB + c] + bias;
        v = v > 0.f ? v : expm1f(v);
        acc += v;
        cacc += 1.f;
    }
    atomicAdd(&pool[curg * EMB + c], acc);
    if (c == 0) atomicAdd(&cnt[curg], cacc);
}

__global__ __launch_bounds__(256) void div_kernel(const float* __restrict__ pool,
                                                  const float* __restrict__ cnt,
                                                  float* __restrict__ out) {
    const int i = blockIdx.x * 256 + threadIdx.x;
    out[i] = pool[i] / fmaxf(cnt[i >> 7], 1.f);
}

// ---------------------------------------------------------------------------
extern "C" void kernel_launch(void* const* d_in, const int* in_sizes, int n_in,
                              void* d_out, int out_size, void* d_ws, size_t ws_size,
                              hipStream_t stream) {
    const float* x      = (const float*)d_in[0];
    const int*   ei     = (const int*)d_in[1];
    const int*   batch  = (const int*)d_in[3];
    const float* W1     = (const float*)d_in[4];
    const float* a_src1 = (const float*)d_in[5];
    const float* a_dst1 = (const float*)d_in[6];
    const float* b1     = (const float*)d_in[7];
    const float* W2     = (const float*)d_in[8];
    const float* a_src2 = (const float*)d_in[9];
    const float* a_dst2 = (const float*)d_in[10];
    const float* b2     = (const float*)d_in[11];
    float* out = (float*)d_out;

    const int N = N_NODES, E = N_EDGES;

    size_t cur_off = 0;
    auto carve = [&](size_t bytes) {
        size_t o = cur_off;
        cur_off = (cur_off + bytes + 255) & ~(size_t)255;
        return (char*)d_ws + o;
    };
    // zero-init region: deg + pool + cnt
    int* deg     = (int*)carve((size_t)N * 4);
    float* pool  = (float*)carve((size_t)N_GRAPHS * EMB * 4);
    float* cnt   = (float*)carve((size_t)N_GRAPHS * 4);
    const size_t zero_bytes = cur_off;
    int* curp    = (int*)carve((size_t)N * 4);
    int* partial = (int*)carve((size_t)SCAN_BLOCKS * 4);
    __bf16* B1h  = (__bf16*)carve((size_t)HEADS * W1_FRAG * 2);
    __bf16* B1l  = (__bf16*)carve((size_t)HEADS * W1_FRAG * 2);
    __bf16* B2h  = (__bf16*)carve((size_t)F1 * EMB * 2);
    __bf16* B2l  = (__bf16*)carve((size_t)F1 * EMB * 2);
    int* off     = (int*)carve((size_t)(N + 1) * 4);
    int* col     = (int*)carve((size_t)E * 4);
    int* rowd    = (int*)carve((size_t)E * 4);
    float4* w4   = (float4*)carve((size_t)E * 16);
    float* aggx  = (float*)carve((size_t)N * HEADS * IN_DIM * 4);
    float* out1  = (float*)carve((size_t)N * F1 * 4);
    float* g2    = (float*)carve((size_t)N * EMB * 4);
    float* out2  = (float*)carve((size_t)N * EMB * 4);
    float* as1   = (float*)carve((size_t)N * HEADS * 4);
    float* ad1   = (float*)carve((size_t)N * HEADS * 4);
    float* as2   = (float*)carve((size_t)N * 4);
    float* ad2   = (float*)carve((size_t)N * 4);

    hipMemsetAsync(d_ws, 0, zero_bytes, stream);

    prep_kernel<<<DEG_BLOCKS + 32, 256, 0, stream>>>(ei, deg, W1, B1h, B1l, W2, B2h, B2l);

    // 3-phase parallel scan (deg -> off), zeroes curp in phase C
    scanA_kernel<<<SCAN_BLOCKS, 256, 0, stream>>>(deg, off, partial, N);
    scanB_kernel<<<1, 256, 0, stream>>>(partial, &off[N]);
    scanC_kernel<<<SCAN_BLOCKS, 256, 0, stream>>>(off, partial, curp, N);

    // gemm1 (x -> as1/ad1) + CSR scatter (col/row), one dispatch
    gemm1_scatter_kernel<<<GEMM1_BLOCKS + DEG_BLOCKS, 256, 0, stream>>>(
        x, B1h, B1l, a_src1, a_dst1, as1, ad1, N, ei, off, curp, col, rowd);

    // per-edge head weights, computed once per edge
    w1_kernel<<<(E + 255) / 256, 256, 0, stream>>>(col, rowd, as1, ad1, w4, E);

    agg1x_kernel<<<(N + 3) / 4, 256, 0, stream>>>(off, col, w4, x, as1, ad1, aggx, N);

    gemm_bd_kernel<<<dim3((N + 63) / 64, HEADS), 256, 0, stream>>>(aggx, B1h, B1l, out1, N);

    gemm2_kernel<<<(N + 63) / 64, 256, 0, stream>>>(out1, B2h, B2l, b1, a_src2, a_dst2,
                                                    g2, as2, ad2, N);
    agg2_kernel<<<(N + 3) / 4, 256, 0, stream>>>(off, col, g2, as2, ad2, out2, N);

    pool_kernel<<<(N + 63) / 64, 128, 0, stream>>>(out2, b2, batch, pool, cnt, N);
    div_kernel<<<(N_GRAPHS * EMB) / 256, 256, 0, stream>>>(pool, cnt, out);
}